// Round 1
// baseline (1127.769 us; speedup 1.0000x reference)
//
#include <hip/hip_runtime.h>
#include <hip/hip_bf16.h>

// Problem constants (StateSpaceLayer): B=2, L=2048, D_MODEL=512, D_STATE=64,
// D_CONV=4, DT_RANK=32. All inputs/outputs fp32.
#define BSZ 2
#define SEQL 2048
#define DM 512
#define DST 64
#define DCONV 4
#define DTR 32
#define NROWS (BSZ * SEQL)   // 4096 flattened (b, t) rows

// ---------------------------------------------------------------------------
// Generic fp32 tiled GEMM:  C[M,N] = A[M,K] @ B[K,N] + bias[N], optional
// softplus activation. BM=64, BN=64, BK=16, 256 threads, 4x4 per thread.
// ---------------------------------------------------------------------------
template <int ACT>
__global__ __launch_bounds__(256) void gemm_bias_kernel(
    const float* __restrict__ A, int lda,
    const float* __restrict__ B, int ldb,
    const float* __restrict__ bias,
    float* __restrict__ C, int ldc,
    int M, int N, int K) {
  constexpr int BM = 64, BN = 64, BK = 16, TM = 4, TN = 4;
  __shared__ float As[BK][BM + 1];
  __shared__ float Bs[BK][BN + 1];

  const int tid = threadIdx.x;
  const int tx = tid % (BN / TN);  // 0..15 (col group)
  const int ty = tid / (BN / TN);  // 0..15 (row group)
  const int bm = blockIdx.y * BM;
  const int bn = blockIdx.x * BN;

  float acc[TM][TN] = {};

  for (int k0 = 0; k0 < K; k0 += BK) {
    // Load A tile (BM x BK)
    for (int i = tid; i < BM * BK; i += 256) {
      int m = i / BK, kk = i % BK;
      float v = 0.f;
      if (bm + m < M && k0 + kk < K) v = A[(size_t)(bm + m) * lda + (k0 + kk)];
      As[kk][m] = v;
    }
    // Load B tile (BK x BN)
    for (int i = tid; i < BK * BN; i += 256) {
      int kk = i / BN, n = i % BN;
      float v = 0.f;
      if (k0 + kk < K && bn + n < N) v = B[(size_t)(k0 + kk) * ldb + (bn + n)];
      Bs[kk][n] = v;
    }
    __syncthreads();
#pragma unroll
    for (int kk = 0; kk < BK; ++kk) {
      float a[TM], b[TN];
#pragma unroll
      for (int i = 0; i < TM; ++i) a[i] = As[kk][ty * TM + i];
#pragma unroll
      for (int j = 0; j < TN; ++j) b[j] = Bs[kk][tx * TN + j];
#pragma unroll
      for (int i = 0; i < TM; ++i)
#pragma unroll
        for (int j = 0; j < TN; ++j) acc[i][j] += a[i] * b[j];
    }
    __syncthreads();
  }

#pragma unroll
  for (int i = 0; i < TM; ++i) {
    int m = bm + ty * TM + i;
    if (m >= M) continue;
#pragma unroll
    for (int j = 0; j < TN; ++j) {
      int n = bn + tx * TN + j;
      if (n >= N) continue;
      float v = acc[i][j] + bias[n];
      if (ACT == 1) {  // softplus
        v = (v > 20.f) ? v : log1pf(expf(v));
      }
      C[(size_t)m * ldc + n] = v;
    }
  }
}

// ---------------------------------------------------------------------------
// Depthwise causal conv1d (K=4): xc[b,t,d] = sum_k w[d,k] * xz[b,t+k-3,d] + cb[d]
// xz is the [NROWS, 2*DM] in_proj output; we read the first half (the x branch).
// ---------------------------------------------------------------------------
__global__ __launch_bounds__(256) void conv_kernel(
    const float* __restrict__ xz, const float* __restrict__ w,
    const float* __restrict__ cb, float* __restrict__ xc) {
  int idx = blockIdx.x * blockDim.x + threadIdx.x;  // over B*L*D
  if (idx >= NROWS * DM) return;
  int d = idx & (DM - 1);
  int t = (idx >> 9) & (SEQL - 1);
  int b = idx >> 20;
  float acc = cb[d];
#pragma unroll
  for (int k = 0; k < DCONV; ++k) {
    int ts = t + k - (DCONV - 1);
    if (ts >= 0)
      acc += w[d * DCONV + k] * xz[((size_t)(b * SEQL + ts)) * (2 * DM) + d];
  }
  xc[idx] = acc;
}

// ---------------------------------------------------------------------------
// Selective scan. One wave (64 lanes) per (b, d) channel; lane = state n.
// h held in one VGPR per lane. y_t via 6-level butterfly reduce each step.
// Loads batched 4 timesteps deep to hide L2 latency at 1 wave/SIMD occupancy.
// ---------------------------------------------------------------------------
__global__ __launch_bounds__(256) void scan_kernel(
    const float* __restrict__ dt,    // [NROWS, DM]
    const float* __restrict__ xc,    // [NROWS, DM]
    const float* __restrict__ xz,    // [NROWS, 2*DM] (z = cols DM..2DM)
    const float* __restrict__ xp,    // [NROWS, 160] (Bp = 32..96, Cp = 96..160)
    const float* __restrict__ A_log, const float* __restrict__ Bpar,
    const float* __restrict__ Cpar, const float* __restrict__ Dpar,
    float* __restrict__ out) {       // [NROWS, DM]
  const int lane = threadIdx.x & 63;
  const int wave = threadIdx.x >> 6;
  const int ch = blockIdx.x * 4 + wave;  // 0..B*DM-1
  const int b = ch >> 9;   // / DM
  const int d = ch & (DM - 1);
  const int n = lane;

  const float aq = -__expf(A_log[d * DST + n]) * 1.44269504f;  // A * log2(e)
  const float bpn = Bpar[d * DST + n];
  const float cpn = Cpar[d * DST + n];
  const float Dd = Dpar[d];
  float h = 0.f;

  const size_t row0 = (size_t)b * SEQL;
  const float* dtp = dt + row0 * DM + d;
  const float* up = xc + row0 * DM + d;
  const float* zp = xz + row0 * (2 * DM) + DM + d;
  const float* bp = xp + row0 * 160 + DTR + n;
  const float* cp = xp + row0 * 160 + DTR + DST + n;
  float* op = out + row0 * DM + d;

  for (int t0 = 0; t0 < SEQL; t0 += 4) {
    float dtv[4], uv[4], zv[4], bpt[4], cpt[4];
#pragma unroll
    for (int j = 0; j < 4; ++j) {
      size_t t = t0 + j;
      dtv[j] = dtp[t * DM];
      uv[j] = up[t * DM];
      zv[j] = zp[t * (2 * DM)];
      bpt[j] = bp[t * 160];
      cpt[j] = cp[t * 160];
    }
#pragma unroll
    for (int j = 0; j < 4; ++j) {
      float Ad = exp2f(dtv[j] * aq);
      float bd = (bpn * bpt[j]) * (dtv[j] * uv[j]);
      h = Ad * h + bd;
      float yt = (cpn * cpt[j]) * h;
#pragma unroll
      for (int off = 32; off >= 1; off >>= 1) yt += __shfl_xor(yt, off, 64);
      if (lane == 0) {
        float y = yt + Dd * uv[j];
        float zz = zv[j];
        float sil = zz / (1.f + expf(-zz));
        op[(size_t)(t0 + j) * DM] = y * sil;
      }
    }
  }
}

// ---------------------------------------------------------------------------
extern "C" void kernel_launch(void* const* d_in, const int* in_sizes, int n_in,
                              void* d_out, int out_size, void* d_ws,
                              size_t ws_size, hipStream_t stream) {
  const float* x = (const float*)d_in[0];           // [B,L,DM]
  const float* in_proj_w = (const float*)d_in[1];   // [DM, 2DM]
  const float* in_proj_b = (const float*)d_in[2];   // [2DM]
  const float* conv_w = (const float*)d_in[3];      // [DM,1,4]
  const float* conv_b = (const float*)d_in[4];      // [DM]
  const float* x_proj_w = (const float*)d_in[5];    // [DM, 160]
  const float* x_proj_b = (const float*)d_in[6];    // [160]
  const float* dt_proj_w = (const float*)d_in[7];   // [32, DM]
  const float* dt_proj_b = (const float*)d_in[8];   // [DM]
  const float* A_log = (const float*)d_in[9];       // [DM, DST]
  const float* B_param = (const float*)d_in[10];    // [DM, DST]
  const float* C_param = (const float*)d_in[11];    // [DM, DST]
  const float* D_param = (const float*)d_in[12];    // [DM]
  float* out = (float*)d_out;

  // Workspace partition (floats)
  float* ws = (float*)d_ws;
  float* xz = ws;                            // NROWS * 2DM = 4,194,304
  float* xc = xz + (size_t)NROWS * 2 * DM;   // NROWS * DM  = 2,097,152
  float* xp = xc + (size_t)NROWS * DM;       // NROWS * 160 =   655,360
  float* dtb = xp + (size_t)NROWS * 160;     // NROWS * DM  = 2,097,152

  // 1) in_proj: xz = x @ in_proj_w + b   [4096 x 1024]
  {
    dim3 grid((2 * DM) / 64, NROWS / 64);
    hipLaunchKernelGGL((gemm_bias_kernel<0>), grid, dim3(256), 0, stream,
                       x, DM, in_proj_w, 2 * DM, in_proj_b, xz, 2 * DM,
                       NROWS, 2 * DM, DM);
  }
  // 2) depthwise causal conv on first half of xz -> xc [4096 x 512]
  {
    int total = NROWS * DM;
    hipLaunchKernelGGL(conv_kernel, dim3((total + 255) / 256), dim3(256), 0,
                       stream, xz, conv_w, conv_b, xc);
  }
  // 3) x_proj: xp = xc @ x_proj_w + b   [4096 x 160]
  {
    dim3 grid((160 + 63) / 64, NROWS / 64);
    hipLaunchKernelGGL((gemm_bias_kernel<0>), grid, dim3(256), 0, stream,
                       xc, DM, x_proj_w, 160, x_proj_b, xp, 160,
                       NROWS, 160, DM);
  }
  // 4) dt = softplus(xp[:, :32] @ dt_proj_w + b)  [4096 x 512]
  {
    dim3 grid(DM / 64, NROWS / 64);
    hipLaunchKernelGGL((gemm_bias_kernel<1>), grid, dim3(256), 0, stream,
                       xp, 160, dt_proj_w, DM, dt_proj_b, dtb, DM,
                       NROWS, DM, DTR);
  }
  // 5) selective scan + skip + gate -> out
  {
    dim3 grid((BSZ * DM) / 4);
    hipLaunchKernelGGL(scan_kernel, grid, dim3(256), 0, stream,
                       dtb, xc, xz, xp, A_log, B_param, C_param, D_param, out);
  }
}

// Round 2
// 448.705 us; speedup vs baseline: 2.5134x; 2.5134x over previous
//
#include <hip/hip_runtime.h>
#include <hip/hip_bf16.h>

// Problem constants (StateSpaceLayer): B=2, L=2048, D_MODEL=512, D_STATE=64,
// D_CONV=4, DT_RANK=32. All inputs/outputs fp32.
#define BSZ 2
#define SEQL 2048
#define DM 512
#define DST 64
#define DCONV 4
#define DTR 32
#define NROWS (BSZ * SEQL)   // 4096 flattened (b, t) rows

// Chunked scan decomposition
#define NC 32   // chunks per sequence
#define CL 64   // chunk length (NC*CL == SEQL)

// ---------------------------------------------------------------------------
// Generic fp32 tiled GEMM:  C[M,N] = A[M,K] @ B[K,N] + bias[N], optional
// softplus activation. BM=64, BN=64, BK=16, 256 threads, 4x4 per thread.
// ---------------------------------------------------------------------------
template <int ACT>
__global__ __launch_bounds__(256) void gemm_bias_kernel(
    const float* __restrict__ A, int lda,
    const float* __restrict__ B, int ldb,
    const float* __restrict__ bias,
    float* __restrict__ C, int ldc,
    int M, int N, int K) {
  constexpr int BM = 64, BN = 64, BK = 16, TM = 4, TN = 4;
  __shared__ float As[BK][BM + 1];
  __shared__ float Bs[BK][BN + 1];

  const int tid = threadIdx.x;
  const int tx = tid % (BN / TN);  // 0..15 (col group)
  const int ty = tid / (BN / TN);  // 0..15 (row group)
  const int bm = blockIdx.y * BM;
  const int bn = blockIdx.x * BN;

  float acc[TM][TN] = {};

  for (int k0 = 0; k0 < K; k0 += BK) {
    for (int i = tid; i < BM * BK; i += 256) {
      int m = i / BK, kk = i % BK;
      float v = 0.f;
      if (bm + m < M && k0 + kk < K) v = A[(size_t)(bm + m) * lda + (k0 + kk)];
      As[kk][m] = v;
    }
    for (int i = tid; i < BK * BN; i += 256) {
      int kk = i / BN, n = i % BN;
      float v = 0.f;
      if (k0 + kk < K && bn + n < N) v = B[(size_t)(k0 + kk) * ldb + (bn + n)];
      Bs[kk][n] = v;
    }
    __syncthreads();
#pragma unroll
    for (int kk = 0; kk < BK; ++kk) {
      float a[TM], b[TN];
#pragma unroll
      for (int i = 0; i < TM; ++i) a[i] = As[kk][ty * TM + i];
#pragma unroll
      for (int j = 0; j < TN; ++j) b[j] = Bs[kk][tx * TN + j];
#pragma unroll
      for (int i = 0; i < TM; ++i)
#pragma unroll
        for (int j = 0; j < TN; ++j) acc[i][j] += a[i] * b[j];
    }
    __syncthreads();
  }

#pragma unroll
  for (int i = 0; i < TM; ++i) {
    int m = bm + ty * TM + i;
    if (m >= M) continue;
#pragma unroll
    for (int j = 0; j < TN; ++j) {
      int n = bn + tx * TN + j;
      if (n >= N) continue;
      float v = acc[i][j] + bias[n];
      if (ACT == 1) {  // softplus
        v = (v > 20.f) ? v : log1pf(expf(v));
      }
      C[(size_t)m * ldc + n] = v;
    }
  }
}

// ---------------------------------------------------------------------------
// Depthwise causal conv1d (K=4)
// ---------------------------------------------------------------------------
__global__ __launch_bounds__(256) void conv_kernel(
    const float* __restrict__ xz, const float* __restrict__ w,
    const float* __restrict__ cb, float* __restrict__ xc) {
  int idx = blockIdx.x * blockDim.x + threadIdx.x;  // over B*L*D
  if (idx >= NROWS * DM) return;
  int d = idx & (DM - 1);
  int t = (idx >> 9) & (SEQL - 1);
  int b = idx >> 20;
  float acc = cb[d];
#pragma unroll
  for (int k = 0; k < DCONV; ++k) {
    int ts = t + k - (DCONV - 1);
    if (ts >= 0)
      acc += w[d * DCONV + k] * xz[((size_t)(b * SEQL + ts)) * (2 * DM) + d];
  }
  xc[idx] = acc;
}

// ---------------------------------------------------------------------------
// Chunked selective scan.
// Wave layout (phases 1 & 3): wid = ch*NC + c, ch = b*DM+d channel, c = chunk.
// lane = state index n. 32768 waves total -> 8 waves/SIMD occupancy.
//
// Phase 1: run recurrence from h=0 over the chunk; emit h_out[n] and sum(dt).
//          (transition product over a chunk = exp2(aq * sum_dt) per lane.)
// Phase 2: per channel, serial combine over the 32 chunk summaries; rewrite
//          hout[] in place with each chunk's true h_in.
// Phase 3: re-run recurrence from h_in; y = reduce_n(C*h) + D*u, gated SiLU.
// ---------------------------------------------------------------------------
__global__ __launch_bounds__(256) void scan_phase1(
    const float* __restrict__ dt, const float* __restrict__ xc,
    const float* __restrict__ xp, const float* __restrict__ A_log,
    const float* __restrict__ Bpar,
    float* __restrict__ hout, float* __restrict__ sdt_arr) {
  const int lane = threadIdx.x & 63;
  const int wid = (blockIdx.x << 2) + (threadIdx.x >> 6);  // ch*NC + c
  const int ch = wid >> 5;        // / NC
  const int c = wid & (NC - 1);
  const int b = ch >> 9;          // / DM
  const int d = ch & (DM - 1);
  const int n = lane;

  const float aq = -__expf(A_log[d * DST + n]) * 1.44269504f;
  const float bpn = Bpar[d * DST + n];
  float h = 0.f, sdt = 0.f;

  const size_t row0 = (size_t)b * SEQL + (size_t)c * CL;
  const float* dtp = dt + row0 * DM + d;
  const float* up = xc + row0 * DM + d;
  const float* bp = xp + row0 * 160 + DTR + n;

  for (int t0 = 0; t0 < CL; t0 += 4) {
    float dtv[4], uv[4], bpt[4];
#pragma unroll
    for (int j = 0; j < 4; ++j) {
      dtv[j] = dtp[(size_t)(t0 + j) * DM];
      uv[j] = up[(size_t)(t0 + j) * DM];
      bpt[j] = bp[(size_t)(t0 + j) * 160];
    }
#pragma unroll
    for (int j = 0; j < 4; ++j) {
      float Ad = exp2f(dtv[j] * aq);
      h = Ad * h + (bpn * bpt[j]) * (dtv[j] * uv[j]);
      sdt += dtv[j];
    }
  }
  hout[(size_t)wid * DST + n] = h;
  if (lane == 0) sdt_arr[wid] = sdt;
}

__global__ __launch_bounds__(256) void scan_phase2(
    const float* __restrict__ A_log, float* __restrict__ hout,
    const float* __restrict__ sdt_arr) {
  const int lane = threadIdx.x & 63;
  const int ch = (blockIdx.x << 2) + (threadIdx.x >> 6);  // 0..B*DM-1
  const int d = ch & (DM - 1);
  const float aq = -__expf(A_log[d * DST + lane]) * 1.44269504f;

  float tmp[NC], pa[NC];
#pragma unroll
  for (int c = 0; c < NC; ++c) {
    tmp[c] = hout[((size_t)ch * NC + c) * DST + lane];
    pa[c] = exp2f(aq * sdt_arr[ch * NC + c]);
  }
  float h = 0.f;
#pragma unroll
  for (int c = 0; c < NC; ++c) {
    hout[((size_t)ch * NC + c) * DST + lane] = h;  // h_in for chunk c
    h = pa[c] * h + tmp[c];
  }
}

__global__ __launch_bounds__(256) void scan_phase3(
    const float* __restrict__ dt, const float* __restrict__ xc,
    const float* __restrict__ xz, const float* __restrict__ xp,
    const float* __restrict__ A_log, const float* __restrict__ Bpar,
    const float* __restrict__ Cpar, const float* __restrict__ Dpar,
    const float* __restrict__ hin, float* __restrict__ out) {
  const int lane = threadIdx.x & 63;
  const int wid = (blockIdx.x << 2) + (threadIdx.x >> 6);  // ch*NC + c
  const int ch = wid >> 5;
  const int c = wid & (NC - 1);
  const int b = ch >> 9;
  const int d = ch & (DM - 1);
  const int n = lane;

  const float aq = -__expf(A_log[d * DST + n]) * 1.44269504f;
  const float bpn = Bpar[d * DST + n];
  const float cpn = Cpar[d * DST + n];
  const float Dd = Dpar[d];
  float h = hin[(size_t)wid * DST + n];

  const size_t row0 = (size_t)b * SEQL + (size_t)c * CL;
  const float* dtp = dt + row0 * DM + d;
  const float* up = xc + row0 * DM + d;
  const float* zp = xz + row0 * (2 * DM) + DM + d;
  const float* bp = xp + row0 * 160 + DTR + n;
  const float* cp = xp + row0 * 160 + DTR + DST + n;
  float* op = out + row0 * DM + d;

  for (int t0 = 0; t0 < CL; t0 += 4) {
    float dtv[4], uv[4], zv[4], bpt[4], cpt[4];
#pragma unroll
    for (int j = 0; j < 4; ++j) {
      dtv[j] = dtp[(size_t)(t0 + j) * DM];
      uv[j] = up[(size_t)(t0 + j) * DM];
      zv[j] = zp[(size_t)(t0 + j) * (2 * DM)];
      bpt[j] = bp[(size_t)(t0 + j) * 160];
      cpt[j] = cp[(size_t)(t0 + j) * 160];
    }
#pragma unroll
    for (int j = 0; j < 4; ++j) {
      float Ad = exp2f(dtv[j] * aq);
      h = Ad * h + (bpn * bpt[j]) * (dtv[j] * uv[j]);
      float yt = (cpn * cpt[j]) * h;
#pragma unroll
      for (int off = 32; off >= 1; off >>= 1) yt += __shfl_xor(yt, off, 64);
      if (lane == 0) {
        float y = yt + Dd * uv[j];
        float zz = zv[j];
        float sil = zz / (1.f + __expf(-zz));
        op[(size_t)(t0 + j) * DM] = y * sil;
      }
    }
  }
}

// ---------------------------------------------------------------------------
extern "C" void kernel_launch(void* const* d_in, const int* in_sizes, int n_in,
                              void* d_out, int out_size, void* d_ws,
                              size_t ws_size, hipStream_t stream) {
  const float* x = (const float*)d_in[0];           // [B,L,DM]
  const float* in_proj_w = (const float*)d_in[1];   // [DM, 2DM]
  const float* in_proj_b = (const float*)d_in[2];   // [2DM]
  const float* conv_w = (const float*)d_in[3];      // [DM,1,4]
  const float* conv_b = (const float*)d_in[4];      // [DM]
  const float* x_proj_w = (const float*)d_in[5];    // [DM, 160]
  const float* x_proj_b = (const float*)d_in[6];    // [160]
  const float* dt_proj_w = (const float*)d_in[7];   // [32, DM]
  const float* dt_proj_b = (const float*)d_in[8];   // [DM]
  const float* A_log = (const float*)d_in[9];       // [DM, DST]
  const float* B_param = (const float*)d_in[10];    // [DM, DST]
  const float* C_param = (const float*)d_in[11];    // [DM, DST]
  const float* D_param = (const float*)d_in[12];    // [DM]
  float* out = (float*)d_out;

  // Workspace partition (floats). Total ~11.2M floats = 44.7 MB.
  float* ws = (float*)d_ws;
  float* xz = ws;                            // NROWS * 2DM  = 4,194,304
  float* xc = xz + (size_t)NROWS * 2 * DM;   // NROWS * DM   = 2,097,152
  float* xp = xc + (size_t)NROWS * DM;       // NROWS * 160  =   655,360
  float* dtb = xp + (size_t)NROWS * 160;     // NROWS * DM   = 2,097,152
  float* hout = dtb + (size_t)NROWS * DM;    // B*DM*NC*DST  = 2,097,152
  float* sdt = hout + (size_t)BSZ * DM * NC * DST;  // B*DM*NC = 32,768

  // 1) in_proj: xz = x @ in_proj_w + b   [4096 x 1024]
  {
    dim3 grid((2 * DM) / 64, NROWS / 64);
    hipLaunchKernelGGL((gemm_bias_kernel<0>), grid, dim3(256), 0, stream,
                       x, DM, in_proj_w, 2 * DM, in_proj_b, xz, 2 * DM,
                       NROWS, 2 * DM, DM);
  }
  // 2) depthwise causal conv on first half of xz -> xc [4096 x 512]
  {
    int total = NROWS * DM;
    hipLaunchKernelGGL(conv_kernel, dim3((total + 255) / 256), dim3(256), 0,
                       stream, xz, conv_w, conv_b, xc);
  }
  // 3) x_proj: xp = xc @ x_proj_w + b   [4096 x 160]
  {
    dim3 grid((160 + 63) / 64, NROWS / 64);
    hipLaunchKernelGGL((gemm_bias_kernel<0>), grid, dim3(256), 0, stream,
                       xc, DM, x_proj_w, 160, x_proj_b, xp, 160,
                       NROWS, 160, DM);
  }
  // 4) dt = softplus(xp[:, :32] @ dt_proj_w + b)  [4096 x 512]
  {
    dim3 grid(DM / 64, NROWS / 64);
    hipLaunchKernelGGL((gemm_bias_kernel<1>), grid, dim3(256), 0, stream,
                       xp, 160, dt_proj_w, DM, dt_proj_b, dtb, DM,
                       NROWS, DM, DTR);
  }
  // 5) chunked selective scan
  {
    dim3 grid((BSZ * DM * NC) / 4);  // 8192 blocks, 4 waves each
    hipLaunchKernelGGL(scan_phase1, grid, dim3(256), 0, stream,
                       dtb, xc, xp, A_log, B_param, hout, sdt);
    hipLaunchKernelGGL(scan_phase2, dim3((BSZ * DM) / 4), dim3(256), 0, stream,
                       A_log, hout, sdt);
    hipLaunchKernelGGL(scan_phase3, grid, dim3(256), 0, stream,
                       dtb, xc, xz, xp, A_log, B_param, C_param, D_param,
                       hout, out);
  }
}

// Round 3
// 385.029 us; speedup vs baseline: 2.9290x; 1.1654x over previous
//
#include <hip/hip_runtime.h>
#include <hip/hip_bf16.h>

// Problem constants (StateSpaceLayer): B=2, L=2048, D_MODEL=512, D_STATE=64,
// D_CONV=4, DT_RANK=32. All inputs/outputs fp32.
#define BSZ 2
#define SEQL 2048
#define DM 512
#define DST 64
#define DCONV 4
#define DTR 32
#define NROWS (BSZ * SEQL)   // 4096 flattened (b, t) rows

// Chunked scan decomposition
#define NC 32   // chunks per sequence
#define CL 64   // chunk length (NC*CL == SEQL)

// ---------------------------------------------------------------------------
// Generic fp32 tiled GEMM:  C[M,N] = A[M,K] @ B[K,N] + bias[N], optional
// softplus activation. BM=64, BN=64, BK=16, 256 threads, 4x4 per thread.
// ---------------------------------------------------------------------------
template <int ACT>
__global__ __launch_bounds__(256) void gemm_bias_kernel(
    const float* __restrict__ A, int lda,
    const float* __restrict__ B, int ldb,
    const float* __restrict__ bias,
    float* __restrict__ C, int ldc,
    int M, int N, int K) {
  constexpr int BM = 64, BN = 64, BK = 16, TM = 4, TN = 4;
  __shared__ float As[BK][BM + 1];
  __shared__ float Bs[BK][BN + 1];

  const int tid = threadIdx.x;
  const int tx = tid % (BN / TN);  // 0..15 (col group)
  const int ty = tid / (BN / TN);  // 0..15 (row group)
  const int bm = blockIdx.y * BM;
  const int bn = blockIdx.x * BN;

  float acc[TM][TN] = {};

  for (int k0 = 0; k0 < K; k0 += BK) {
    for (int i = tid; i < BM * BK; i += 256) {
      int m = i / BK, kk = i % BK;
      float v = 0.f;
      if (bm + m < M && k0 + kk < K) v = A[(size_t)(bm + m) * lda + (k0 + kk)];
      As[kk][m] = v;
    }
    for (int i = tid; i < BK * BN; i += 256) {
      int kk = i / BN, n = i % BN;
      float v = 0.f;
      if (k0 + kk < K && bn + n < N) v = B[(size_t)(k0 + kk) * ldb + (bn + n)];
      Bs[kk][n] = v;
    }
    __syncthreads();
#pragma unroll
    for (int kk = 0; kk < BK; ++kk) {
      float a[TM], b[TN];
#pragma unroll
      for (int i = 0; i < TM; ++i) a[i] = As[kk][ty * TM + i];
#pragma unroll
      for (int j = 0; j < TN; ++j) b[j] = Bs[kk][tx * TN + j];
#pragma unroll
      for (int i = 0; i < TM; ++i)
#pragma unroll
        for (int j = 0; j < TN; ++j) acc[i][j] += a[i] * b[j];
    }
    __syncthreads();
  }

#pragma unroll
  for (int i = 0; i < TM; ++i) {
    int m = bm + ty * TM + i;
    if (m >= M) continue;
#pragma unroll
    for (int j = 0; j < TN; ++j) {
      int n = bn + tx * TN + j;
      if (n >= N) continue;
      float v = acc[i][j] + bias[n];
      if (ACT == 1) {  // softplus
        v = (v > 20.f) ? v : log1pf(expf(v));
      }
      C[(size_t)m * ldc + n] = v;
    }
  }
}

// ---------------------------------------------------------------------------
// Depthwise causal conv1d (K=4)
// ---------------------------------------------------------------------------
__global__ __launch_bounds__(256) void conv_kernel(
    const float* __restrict__ xz, const float* __restrict__ w,
    const float* __restrict__ cb, float* __restrict__ xc) {
  int idx = blockIdx.x * blockDim.x + threadIdx.x;  // over B*L*D
  if (idx >= NROWS * DM) return;
  int d = idx & (DM - 1);
  int t = (idx >> 9) & (SEQL - 1);
  int b = idx >> 20;
  float acc = cb[d];
#pragma unroll
  for (int k = 0; k < DCONV; ++k) {
    int ts = t + k - (DCONV - 1);
    if (ts >= 0)
      acc += w[d * DCONV + k] * xz[((size_t)(b * SEQL + ts)) * (2 * DM) + d];
  }
  xc[idx] = acc;
}

// ---------------------------------------------------------------------------
// Chunked selective scan.
// Wave layout (phases 1 & 3): wid = ch*NC + c, ch = b*DM+d channel, c = chunk.
// lane = state index n. 32768 waves total -> high occupancy.
//
// Phase 1: run recurrence from h=0 over the chunk; emit h_out[n] and sum(dt).
// Phase 2: per channel, serial combine over the 32 chunk summaries (in place).
// Phase 3: re-run recurrence from h_in. y-reduction is DEFERRED: per 16-step
//          tile each lane writes W[t][n]=Cw*h to a per-wave LDS tile, then a
//          wave-parallel reduce (float4 quarter-row sums + 2 shfl) and a
//          16-lane epilogue (skip + SiLU gate + store). Replaces the per-step
//          6-shfl butterfly (12 ops/t -> ~1.5 ops/t amortized).
// ---------------------------------------------------------------------------
__global__ __launch_bounds__(256) void scan_phase1(
    const float* __restrict__ dt, const float* __restrict__ xc,
    const float* __restrict__ xp, const float* __restrict__ A_log,
    const float* __restrict__ Bpar,
    float* __restrict__ hout, float* __restrict__ sdt_arr) {
  const int lane = threadIdx.x & 63;
  const int wid = (blockIdx.x << 2) + (threadIdx.x >> 6);  // ch*NC + c
  const int ch = wid >> 5;        // / NC
  const int c = wid & (NC - 1);
  const int b = ch >> 9;          // / DM
  const int d = ch & (DM - 1);
  const int n = lane;

  const float aq = -__expf(A_log[d * DST + n]) * 1.44269504f;
  const float bpn = Bpar[d * DST + n];
  float h = 0.f, sdt = 0.f;

  const size_t row0 = (size_t)b * SEQL + (size_t)c * CL;
  const float* dtp = dt + row0 * DM + d;
  const float* up = xc + row0 * DM + d;
  const float* bp = xp + row0 * 160 + DTR + n;

  for (int t0 = 0; t0 < CL; t0 += 4) {
    float dtv[4], uv[4], bpt[4];
#pragma unroll
    for (int j = 0; j < 4; ++j) {
      dtv[j] = dtp[(size_t)(t0 + j) * DM];
      uv[j] = up[(size_t)(t0 + j) * DM];
      bpt[j] = bp[(size_t)(t0 + j) * 160];
    }
#pragma unroll
    for (int j = 0; j < 4; ++j) {
      float Ad = exp2f(dtv[j] * aq);
      h = Ad * h + (bpn * bpt[j]) * (dtv[j] * uv[j]);
      sdt += dtv[j];
    }
  }
  hout[(size_t)wid * DST + n] = h;
  if (lane == 0) sdt_arr[wid] = sdt;
}

__global__ __launch_bounds__(256) void scan_phase2(
    const float* __restrict__ A_log, float* __restrict__ hout,
    const float* __restrict__ sdt_arr) {
  const int lane = threadIdx.x & 63;
  const int ch = (blockIdx.x << 2) + (threadIdx.x >> 6);  // 0..B*DM-1
  const int d = ch & (DM - 1);
  const float aq = -__expf(A_log[d * DST + lane]) * 1.44269504f;

  float tmp[NC], pa[NC];
#pragma unroll
  for (int c = 0; c < NC; ++c) {
    tmp[c] = hout[((size_t)ch * NC + c) * DST + lane];
    pa[c] = exp2f(aq * sdt_arr[ch * NC + c]);
  }
  float h = 0.f;
#pragma unroll
  for (int c = 0; c < NC; ++c) {
    hout[((size_t)ch * NC + c) * DST + lane] = h;  // h_in for chunk c
    h = pa[c] * h + tmp[c];
  }
}

__global__ __launch_bounds__(256) void scan_phase3(
    const float* __restrict__ dt, const float* __restrict__ xc,
    const float* __restrict__ xz, const float* __restrict__ xp,
    const float* __restrict__ A_log, const float* __restrict__ Bpar,
    const float* __restrict__ Cpar, const float* __restrict__ Dpar,
    const float* __restrict__ hin, float* __restrict__ out) {
  // Per-wave LDS tile: 16 timesteps x 64 states, pad to 68 (write: 2-way free;
  // float4 read: 16B-aligned, bank-balanced). 4*16*68*4 = 17408 B per block.
  __shared__ float W[4][16][68];

  const int lane = threadIdx.x & 63;
  const int wave = threadIdx.x >> 6;
  const int wid = (blockIdx.x << 2) + wave;  // ch*NC + c
  const int ch = wid >> 5;
  const int c = wid & (NC - 1);
  const int b = ch >> 9;
  const int d = ch & (DM - 1);
  const int n = lane;

  const float aq = -__expf(A_log[d * DST + n]) * 1.44269504f;
  const float bpn = Bpar[d * DST + n];
  const float cpn = Cpar[d * DST + n];
  const float Dd = Dpar[d];
  float h = hin[(size_t)wid * DST + n];

  const size_t row0 = (size_t)b * SEQL + (size_t)c * CL;
  const float* dtp = dt + row0 * DM + d;
  const float* up = xc + row0 * DM + d;
  const float* bp = xp + row0 * 160 + DTR + n;
  const float* cp = xp + row0 * 160 + DTR + DST + n;

  const int tt = lane & 15;   // timestep owned in reduce
  const int q = lane >> 4;    // quarter of the n-range summed

  for (int t0 = 0; t0 < CL; t0 += 16) {
    // --- recurrence for 16 steps, W[t][n] = C_n*Cp_t,n*h_t,n ---
#pragma unroll
    for (int g = 0; g < 16; g += 4) {
      float dtv[4], uv[4], bpt[4], cpt[4];
#pragma unroll
      for (int j = 0; j < 4; ++j) {
        size_t t = (size_t)(t0 + g + j);
        dtv[j] = dtp[t * DM];
        uv[j] = up[t * DM];
        bpt[j] = bp[t * 160];
        cpt[j] = cp[t * 160];
      }
#pragma unroll
      for (int j = 0; j < 4; ++j) {
        float Ad = exp2f(dtv[j] * aq);
        h = Ad * h + (bpn * bpt[j]) * (dtv[j] * uv[j]);
        W[wave][g + j][n] = (cpn * cpt[j]) * h;
      }
    }
    // --- wave-parallel reduce over n (per-wave tile; no barrier needed) ---
    const float4* wr = (const float4*)&W[wave][tt][q * 16];
    float s = 0.f;
#pragma unroll
    for (int k2 = 0; k2 < 4; ++k2) {
      float4 v = wr[k2];
      s += (v.x + v.y) + (v.z + v.w);
    }
    s += __shfl_xor(s, 16, 64);
    s += __shfl_xor(s, 32, 64);
    // --- epilogue: 16 lanes, one timestep each ---
    if (lane < 16) {
      size_t t = (size_t)(t0 + lane);
      float u = up[t * DM];
      float zz = xz[(row0 + t) * (2 * DM) + DM + d];
      float y = s + Dd * u;
      float sil = zz / (1.f + __expf(-zz));
      out[(row0 + t) * DM + d] = y * sil;
    }
  }
}

// ---------------------------------------------------------------------------
extern "C" void kernel_launch(void* const* d_in, const int* in_sizes, int n_in,
                              void* d_out, int out_size, void* d_ws,
                              size_t ws_size, hipStream_t stream) {
  const float* x = (const float*)d_in[0];           // [B,L,DM]
  const float* in_proj_w = (const float*)d_in[1];   // [DM, 2DM]
  const float* in_proj_b = (const float*)d_in[2];   // [2DM]
  const float* conv_w = (const float*)d_in[3];      // [DM,1,4]
  const float* conv_b = (const float*)d_in[4];      // [DM]
  const float* x_proj_w = (const float*)d_in[5];    // [DM, 160]
  const float* x_proj_b = (const float*)d_in[6];    // [160]
  const float* dt_proj_w = (const float*)d_in[7];   // [32, DM]
  const float* dt_proj_b = (const float*)d_in[8];   // [DM]
  const float* A_log = (const float*)d_in[9];       // [DM, DST]
  const float* B_param = (const float*)d_in[10];    // [DM, DST]
  const float* C_param = (const float*)d_in[11];    // [DM, DST]
  const float* D_param = (const float*)d_in[12];    // [DM]
  float* out = (float*)d_out;

  // Workspace partition (floats). Total ~11.2M floats = 44.7 MB.
  float* ws = (float*)d_ws;
  float* xz = ws;                            // NROWS * 2DM  = 4,194,304
  float* xc = xz + (size_t)NROWS * 2 * DM;   // NROWS * DM   = 2,097,152
  float* xp = xc + (size_t)NROWS * DM;       // NROWS * 160  =   655,360
  float* dtb = xp + (size_t)NROWS * 160;     // NROWS * DM   = 2,097,152
  float* hout = dtb + (size_t)NROWS * DM;    // B*DM*NC*DST  = 2,097,152
  float* sdt = hout + (size_t)BSZ * DM * NC * DST;  // B*DM*NC = 32,768

  // 1) in_proj: xz = x @ in_proj_w + b   [4096 x 1024]
  {
    dim3 grid((2 * DM) / 64, NROWS / 64);
    hipLaunchKernelGGL((gemm_bias_kernel<0>), grid, dim3(256), 0, stream,
                       x, DM, in_proj_w, 2 * DM, in_proj_b, xz, 2 * DM,
                       NROWS, 2 * DM, DM);
  }
  // 2) depthwise causal conv on first half of xz -> xc [4096 x 512]
  {
    int total = NROWS * DM;
    hipLaunchKernelGGL(conv_kernel, dim3((total + 255) / 256), dim3(256), 0,
                       stream, xz, conv_w, conv_b, xc);
  }
  // 3) x_proj: xp = xc @ x_proj_w + b   [4096 x 160]
  {
    dim3 grid((160 + 63) / 64, NROWS / 64);
    hipLaunchKernelGGL((gemm_bias_kernel<0>), grid, dim3(256), 0, stream,
                       xc, DM, x_proj_w, 160, x_proj_b, xp, 160,
                       NROWS, 160, DM);
  }
  // 4) dt = softplus(xp[:, :32] @ dt_proj_w + b)  [4096 x 512]
  {
    dim3 grid(DM / 64, NROWS / 64);
    hipLaunchKernelGGL((gemm_bias_kernel<1>), grid, dim3(256), 0, stream,
                       xp, 160, dt_proj_w, DM, dt_proj_b, dtb, DM,
                       NROWS, DM, DTR);
  }
  // 5) chunked selective scan
  {
    dim3 grid((BSZ * DM * NC) / 4);  // 8192 blocks, 4 waves each
    hipLaunchKernelGGL(scan_phase1, grid, dim3(256), 0, stream,
                       dtb, xc, xp, A_log, B_param, hout, sdt);
    hipLaunchKernelGGL(scan_phase2, dim3((BSZ * DM) / 4), dim3(256), 0, stream,
                       A_log, hout, sdt);
    hipLaunchKernelGGL(scan_phase3, grid, dim3(256), 0, stream,
                       dtb, xc, xz, xp, A_log, B_param, C_param, D_param,
                       hout, out);
  }
}

// Round 4
// 307.674 us; speedup vs baseline: 3.6655x; 1.2514x over previous
//
#include <hip/hip_runtime.h>
#include <hip/hip_bf16.h>

// Problem constants (StateSpaceLayer): B=2, L=2048, D_MODEL=512, D_STATE=64,
// D_CONV=4, DT_RANK=32. All inputs/outputs fp32.
#define BSZ 2
#define SEQL 2048
#define DM 512
#define DST 64
#define DCONV 4
#define DTR 32
#define NROWS (BSZ * SEQL)   // 4096 flattened (b, t) rows

// Chunked scan decomposition
#define NC 32   // chunks per sequence
#define CL 64   // chunk length (NC*CL == SEQL)

typedef unsigned short u16;
typedef short bf16x8 __attribute__((ext_vector_type(8)));
typedef float f32x4 __attribute__((ext_vector_type(4)));

// fp32 -> bf16 RNE split helpers (bit ops; avoids __hip_bfloat16 ABI variance)
__device__ __forceinline__ u16 f2bf(float f) {
  unsigned u = __float_as_uint(f);
  return (u16)((u + 0x7FFFu + ((u >> 16) & 1u)) >> 16);
}
__device__ __forceinline__ float bf2f(u16 h) {
  return __uint_as_float(((unsigned)h) << 16);
}

// async global->LDS, 16B per lane (dest = wave-uniform base + lane*16)
__device__ __forceinline__ void gload_lds16(const u16* g, u16* l) {
  __builtin_amdgcn_global_load_lds(
      (const __attribute__((address_space(1))) void*)(const void*)g,
      (__attribute__((address_space(3))) void*)(void*)l, 16, 0, 0);
}

// ---------------------------------------------------------------------------
// Generic fp32 tiled GEMM (kept for x_proj / dt_proj):
// C[M,N] = A[M,K] @ B[K,N] + bias[N], optional softplus.
// ---------------------------------------------------------------------------
template <int ACT>
__global__ __launch_bounds__(256) void gemm_bias_kernel(
    const float* __restrict__ A, int lda,
    const float* __restrict__ B, int ldb,
    const float* __restrict__ bias,
    float* __restrict__ C, int ldc,
    int M, int N, int K) {
  constexpr int BM = 64, BN = 64, BK = 16, TM = 4, TN = 4;
  __shared__ float As[BK][BM + 1];
  __shared__ float Bs[BK][BN + 1];

  const int tid = threadIdx.x;
  const int tx = tid % (BN / TN);
  const int ty = tid / (BN / TN);
  const int bm = blockIdx.y * BM;
  const int bn = blockIdx.x * BN;

  float acc[TM][TN] = {};

  for (int k0 = 0; k0 < K; k0 += BK) {
    for (int i = tid; i < BM * BK; i += 256) {
      int m = i / BK, kk = i % BK;
      float v = 0.f;
      if (bm + m < M && k0 + kk < K) v = A[(size_t)(bm + m) * lda + (k0 + kk)];
      As[kk][m] = v;
    }
    for (int i = tid; i < BK * BN; i += 256) {
      int kk = i / BN, n = i % BN;
      float v = 0.f;
      if (k0 + kk < K && bn + n < N) v = B[(size_t)(k0 + kk) * ldb + (bn + n)];
      Bs[kk][n] = v;
    }
    __syncthreads();
#pragma unroll
    for (int kk = 0; kk < BK; ++kk) {
      float a[TM], b[TN];
#pragma unroll
      for (int i = 0; i < TM; ++i) a[i] = As[kk][ty * TM + i];
#pragma unroll
      for (int j = 0; j < TN; ++j) b[j] = Bs[kk][tx * TN + j];
#pragma unroll
      for (int i = 0; i < TM; ++i)
#pragma unroll
        for (int j = 0; j < TN; ++j) acc[i][j] += a[i] * b[j];
    }
    __syncthreads();
  }

#pragma unroll
  for (int i = 0; i < TM; ++i) {
    int m = bm + ty * TM + i;
    if (m >= M) continue;
#pragma unroll
    for (int j = 0; j < TN; ++j) {
      int n = bn + tx * TN + j;
      if (n >= N) continue;
      float v = acc[i][j] + bias[n];
      if (ACT == 1) v = (v > 20.f) ? v : log1pf(expf(v));
      C[(size_t)m * ldc + n] = v;
    }
  }
}

// ---------------------------------------------------------------------------
// Split conversion kernels for in_proj operands.
// split_x: x [4096][512] f32 -> A_hi, A_lo bf16 (row-major)
// split_w: W [512][1024] f32 -> Wt_hi, Wt_lo bf16 TRANSPOSED [1024][512]
// ---------------------------------------------------------------------------
__global__ __launch_bounds__(256) void split_x_kernel(
    const float* __restrict__ x, u16* __restrict__ hi, u16* __restrict__ lo) {
  int idx = (blockIdx.x * 256 + threadIdx.x) * 4;  // over NROWS*DM
  float4 v = *(const float4*)(x + idx);
  ushort4 h, l;
  h.x = f2bf(v.x); l.x = f2bf(v.x - bf2f(h.x));
  h.y = f2bf(v.y); l.y = f2bf(v.y - bf2f(h.y));
  h.z = f2bf(v.z); l.z = f2bf(v.z - bf2f(h.z));
  h.w = f2bf(v.w); l.w = f2bf(v.w - bf2f(h.w));
  *(ushort4*)(hi + idx) = h;
  *(ushort4*)(lo + idx) = l;
}

__global__ __launch_bounds__(256) void split_w_kernel(
    const float* __restrict__ W, u16* __restrict__ Wt_hi,
    u16* __restrict__ Wt_lo) {
  __shared__ u16 shi[32][33], slo[32][33];
  const int n0 = blockIdx.x * 32;  // 32 blocks over N=1024
  const int k0 = blockIdx.y * 32;  // 16 blocks over K=512
  const int i = threadIdx.x >> 5;  // 0..7
  const int j = threadIdx.x & 31;
#pragma unroll
  for (int r = 0; r < 4; ++r) {
    int k = i + r * 8;
    float v = W[(size_t)(k0 + k) * 1024 + n0 + j];
    u16 h = f2bf(v);
    shi[k][j] = h;
    slo[k][j] = f2bf(v - bf2f(h));
  }
  __syncthreads();
#pragma unroll
  for (int r = 0; r < 4; ++r) {
    int n = i + r * 8;  // row of Wt within tile
    Wt_hi[(size_t)(n0 + n) * 512 + k0 + j] = shi[j][n];
    Wt_lo[(size_t)(n0 + n) * 512 + k0 + j] = slo[j][n];
  }
}

// ---------------------------------------------------------------------------
// in_proj split-bf16 MFMA GEMM: C[4096][1024] = A[4096][512] @ W[512][1024]+b
//   C = Ah@Wh + Ah@Wl + Al@Wh  (fp32 MFMA accumulation; lo*lo dropped)
// Tile 128x128xBK32, 4 waves (each 64x64: 4x4 frags of 16x16x32 bf16 MFMA).
// LDS: 4 arrays [128 rows][32 k] bf16, 8KB each. XOR swizzle on the 16B
// quarter index (q ^= (row>>1)&3) applied BOTH on the pre-swizzled global
// source (linear global_load_lds dest) and on the ds_read -> 2-way free.
// ---------------------------------------------------------------------------
__global__ __launch_bounds__(256) void in_proj_mfma_kernel(
    const u16* __restrict__ A_hi, const u16* __restrict__ A_lo,
    const u16* __restrict__ Bt_hi, const u16* __restrict__ Bt_lo,
    const float* __restrict__ bias, float* __restrict__ C) {
  __shared__ alignas(16) u16 sAh[4096], sAl[4096], sBh[4096], sBl[4096];

  const int lane = threadIdx.x & 63;
  const int wv = threadIdx.x >> 6;
  const int bm = blockIdx.y * 128;
  const int bn = blockIdx.x * 128;
  const int fr = lane & 15;   // fragment row/col index
  const int q = lane >> 4;    // k-quarter (8 bf16 = 16B)

  // Staging geometry: 8 chunks of 16 rows x 32 k (1KB) per array; wave wv
  // stages chunks {wv, wv+4}. Lane l -> row = c*16 + l/4, dest quarter l%4,
  // source quarter pre-swizzled.
  const int st_rowc = lane >> 2;
  const int st_qd = lane & 3;

  // Per-thread constant LDS read offsets (element units), swizzled.
  const bf16x8 *pAh[4], *pAl[4], *pBh[4], *pBl[4];
#pragma unroll
  for (int t = 0; t < 4; ++t) {
    int ra = (wv >> 1) * 64 + t * 16 + fr;
    int ea = ra * 32 + ((q ^ ((ra >> 1) & 3)) * 8);
    pAh[t] = (const bf16x8*)(sAh + ea);
    pAl[t] = (const bf16x8*)(sAl + ea);
    int rb = (wv & 1) * 64 + t * 16 + fr;
    int eb = rb * 32 + ((q ^ ((rb >> 1) & 3)) * 8);
    pBh[t] = (const bf16x8*)(sBh + eb);
    pBl[t] = (const bf16x8*)(sBl + eb);
  }

  f32x4 zero = {0.f, 0.f, 0.f, 0.f};
  f32x4 acc[4][4];
#pragma unroll
  for (int i = 0; i < 4; ++i)
#pragma unroll
    for (int j = 0; j < 4; ++j) acc[i][j] = zero;

  auto stage = [&](int k0) {
#pragma unroll
    for (int i = 0; i < 2; ++i) {
      int c = wv + i * 4;
      int row = c * 16 + st_rowc;
      int qs = st_qd ^ ((row >> 1) & 3);
      size_t ga = (size_t)(bm + row) * 512 + k0 + qs * 8;
      size_t gb = (size_t)(bn + row) * 512 + k0 + qs * 8;
      gload_lds16(A_hi + ga, sAh + c * 512);
      gload_lds16(A_lo + ga, sAl + c * 512);
      gload_lds16(Bt_hi + gb, sBh + c * 512);
      gload_lds16(Bt_lo + gb, sBl + c * 512);
    }
  };

  stage(0);
  for (int kt = 0; kt < 16; ++kt) {
    __syncthreads();  // staging of tile kt complete (vmcnt(0) auto-inserted)
    bf16x8 ah[4], al[4], bh[4], bl[4];
#pragma unroll
    for (int t = 0; t < 4; ++t) {
      ah[t] = *pAh[t];
      al[t] = *pAl[t];
      bh[t] = *pBh[t];
      bl[t] = *pBl[t];
    }
    __syncthreads();  // all waves done reading LDS (lgkmcnt drained first)
    if (kt < 15) stage((kt + 1) * 32);  // async prefetch overlaps MFMAs
#pragma unroll
    for (int mi = 0; mi < 4; ++mi)
#pragma unroll
      for (int nj = 0; nj < 4; ++nj) {
        f32x4 a = acc[mi][nj];
        a = __builtin_amdgcn_mfma_f32_16x16x32_bf16(al[mi], bh[nj], a, 0, 0, 0);
        a = __builtin_amdgcn_mfma_f32_16x16x32_bf16(ah[mi], bl[nj], a, 0, 0, 0);
        a = __builtin_amdgcn_mfma_f32_16x16x32_bf16(ah[mi], bh[nj], a, 0, 0, 0);
        acc[mi][nj] = a;
      }
  }

  // Epilogue: D col = lane&15, row = (lane>>4)*4 + reg
#pragma unroll
  for (int mi = 0; mi < 4; ++mi) {
#pragma unroll
    for (int nj = 0; nj < 4; ++nj) {
      int row = bm + (wv >> 1) * 64 + mi * 16 + q * 4;
      int col = bn + (wv & 1) * 64 + nj * 16 + fr;
      float bs = bias[col];
#pragma unroll
      for (int e = 0; e < 4; ++e)
        C[(size_t)(row + e) * 1024 + col] = acc[mi][nj][e] + bs;
    }
  }
}

// ---------------------------------------------------------------------------
// Depthwise causal conv1d (K=4)
// ---------------------------------------------------------------------------
__global__ __launch_bounds__(256) void conv_kernel(
    const float* __restrict__ xz, const float* __restrict__ w,
    const float* __restrict__ cb, float* __restrict__ xc) {
  int idx = blockIdx.x * blockDim.x + threadIdx.x;  // over B*L*D
  if (idx >= NROWS * DM) return;
  int d = idx & (DM - 1);
  int t = (idx >> 9) & (SEQL - 1);
  int b = idx >> 20;
  float acc = cb[d];
#pragma unroll
  for (int k = 0; k < DCONV; ++k) {
    int ts = t + k - (DCONV - 1);
    if (ts >= 0)
      acc += w[d * DCONV + k] * xz[((size_t)(b * SEQL + ts)) * (2 * DM) + d];
  }
  xc[idx] = acc;
}

// ---------------------------------------------------------------------------
// Chunked selective scan (unchanged from R2): phase1 summaries, phase2
// combine, phase3 recompute + deferred LDS y-reduce + gate.
// ---------------------------------------------------------------------------
__global__ __launch_bounds__(256) void scan_phase1(
    const float* __restrict__ dt, const float* __restrict__ xc,
    const float* __restrict__ xp, const float* __restrict__ A_log,
    const float* __restrict__ Bpar,
    float* __restrict__ hout, float* __restrict__ sdt_arr) {
  const int lane = threadIdx.x & 63;
  const int wid = (blockIdx.x << 2) + (threadIdx.x >> 6);  // ch*NC + c
  const int ch = wid >> 5;
  const int c = wid & (NC - 1);
  const int b = ch >> 9;
  const int d = ch & (DM - 1);
  const int n = lane;

  const float aq = -__expf(A_log[d * DST + n]) * 1.44269504f;
  const float bpn = Bpar[d * DST + n];
  float h = 0.f, sdt = 0.f;

  const size_t row0 = (size_t)b * SEQL + (size_t)c * CL;
  const float* dtp = dt + row0 * DM + d;
  const float* up = xc + row0 * DM + d;
  const float* bp = xp + row0 * 160 + DTR + n;

  for (int t0 = 0; t0 < CL; t0 += 4) {
    float dtv[4], uv[4], bpt[4];
#pragma unroll
    for (int j = 0; j < 4; ++j) {
      dtv[j] = dtp[(size_t)(t0 + j) * DM];
      uv[j] = up[(size_t)(t0 + j) * DM];
      bpt[j] = bp[(size_t)(t0 + j) * 160];
    }
#pragma unroll
    for (int j = 0; j < 4; ++j) {
      float Ad = exp2f(dtv[j] * aq);
      h = Ad * h + (bpn * bpt[j]) * (dtv[j] * uv[j]);
      sdt += dtv[j];
    }
  }
  hout[(size_t)wid * DST + n] = h;
  if (lane == 0) sdt_arr[wid] = sdt;
}

__global__ __launch_bounds__(256) void scan_phase2(
    const float* __restrict__ A_log, float* __restrict__ hout,
    const float* __restrict__ sdt_arr) {
  const int lane = threadIdx.x & 63;
  const int ch = (blockIdx.x << 2) + (threadIdx.x >> 6);
  const int d = ch & (DM - 1);
  const float aq = -__expf(A_log[d * DST + lane]) * 1.44269504f;

  float tmp[NC], pa[NC];
#pragma unroll
  for (int c = 0; c < NC; ++c) {
    tmp[c] = hout[((size_t)ch * NC + c) * DST + lane];
    pa[c] = exp2f(aq * sdt_arr[ch * NC + c]);
  }
  float h = 0.f;
#pragma unroll
  for (int c = 0; c < NC; ++c) {
    hout[((size_t)ch * NC + c) * DST + lane] = h;
    h = pa[c] * h + tmp[c];
  }
}

__global__ __launch_bounds__(256) void scan_phase3(
    const float* __restrict__ dt, const float* __restrict__ xc,
    const float* __restrict__ xz, const float* __restrict__ xp,
    const float* __restrict__ A_log, const float* __restrict__ Bpar,
    const float* __restrict__ Cpar, const float* __restrict__ Dpar,
    const float* __restrict__ hin, float* __restrict__ out) {
  __shared__ float W[4][16][68];

  const int lane = threadIdx.x & 63;
  const int wave = threadIdx.x >> 6;
  const int wid = (blockIdx.x << 2) + wave;
  const int ch = wid >> 5;
  const int c = wid & (NC - 1);
  const int b = ch >> 9;
  const int d = ch & (DM - 1);
  const int n = lane;

  const float aq = -__expf(A_log[d * DST + n]) * 1.44269504f;
  const float bpn = Bpar[d * DST + n];
  const float cpn = Cpar[d * DST + n];
  const float Dd = Dpar[d];
  float h = hin[(size_t)wid * DST + n];

  const size_t row0 = (size_t)b * SEQL + (size_t)c * CL;
  const float* dtp = dt + row0 * DM + d;
  const float* up = xc + row0 * DM + d;
  const float* bp = xp + row0 * 160 + DTR + n;
  const float* cp = xp + row0 * 160 + DTR + DST + n;

  const int tt = lane & 15;
  const int q = lane >> 4;

  for (int t0 = 0; t0 < CL; t0 += 16) {
#pragma unroll
    for (int g = 0; g < 16; g += 4) {
      float dtv[4], uv[4], bpt[4], cpt[4];
#pragma unroll
      for (int j = 0; j < 4; ++j) {
        size_t t = (size_t)(t0 + g + j);
        dtv[j] = dtp[t * DM];
        uv[j] = up[t * DM];
        bpt[j] = bp[t * 160];
        cpt[j] = cp[t * 160];
      }
#pragma unroll
      for (int j = 0; j < 4; ++j) {
        float Ad = exp2f(dtv[j] * aq);
        h = Ad * h + (bpn * bpt[j]) * (dtv[j] * uv[j]);
        W[wave][g + j][n] = (cpn * cpt[j]) * h;
      }
    }
    const float4* wr = (const float4*)&W[wave][tt][q * 16];
    float s = 0.f;
#pragma unroll
    for (int k2 = 0; k2 < 4; ++k2) {
      float4 v = wr[k2];
      s += (v.x + v.y) + (v.z + v.w);
    }
    s += __shfl_xor(s, 16, 64);
    s += __shfl_xor(s, 32, 64);
    if (lane < 16) {
      size_t t = (size_t)(t0 + lane);
      float u = up[t * DM];
      float zz = xz[(row0 + t) * (2 * DM) + DM + d];
      float y = s + Dd * u;
      float sil = zz / (1.f + __expf(-zz));
      out[(row0 + t) * DM + d] = y * sil;
    }
  }
}

// ---------------------------------------------------------------------------
extern "C" void kernel_launch(void* const* d_in, const int* in_sizes, int n_in,
                              void* d_out, int out_size, void* d_ws,
                              size_t ws_size, hipStream_t stream) {
  const float* x = (const float*)d_in[0];           // [B,L,DM]
  const float* in_proj_w = (const float*)d_in[1];   // [DM, 2DM]
  const float* in_proj_b = (const float*)d_in[2];   // [2DM]
  const float* conv_w = (const float*)d_in[3];      // [DM,1,4]
  const float* conv_b = (const float*)d_in[4];      // [DM]
  const float* x_proj_w = (const float*)d_in[5];    // [DM, 160]
  const float* x_proj_b = (const float*)d_in[6];    // [160]
  const float* dt_proj_w = (const float*)d_in[7];   // [32, DM]
  const float* dt_proj_b = (const float*)d_in[8];   // [DM]
  const float* A_log = (const float*)d_in[9];       // [DM, DST]
  const float* B_param = (const float*)d_in[10];    // [DM, DST]
  const float* C_param = (const float*)d_in[11];    // [DM, DST]
  const float* D_param = (const float*)d_in[12];    // [DM]
  float* out = (float*)d_out;

  // Workspace partition. Floats: ~44.8 MB, then bf16 split arrays (+10.5 MB).
  float* ws = (float*)d_ws;
  float* xz = ws;                            // NROWS * 2DM  = 4,194,304
  float* xc = xz + (size_t)NROWS * 2 * DM;   // NROWS * DM   = 2,097,152
  float* xp = xc + (size_t)NROWS * DM;       // NROWS * 160  =   655,360
  float* dtb = xp + (size_t)NROWS * 160;     // NROWS * DM   = 2,097,152
  float* hout = dtb + (size_t)NROWS * DM;    // B*DM*NC*DST  = 2,097,152
  float* sdt = hout + (size_t)BSZ * DM * NC * DST;  // B*DM*NC = 32,768
  u16* A_hi = (u16*)(sdt + (size_t)BSZ * DM * NC);
  u16* A_lo = A_hi + (size_t)NROWS * DM;     // each 2,097,152 u16
  u16* Wt_hi = A_lo + (size_t)NROWS * DM;    // [1024][512] = 524,288 u16
  u16* Wt_lo = Wt_hi + (size_t)1024 * 512;

  // 0) split conversions for in_proj operands
  hipLaunchKernelGGL(split_x_kernel, dim3((NROWS * DM) / (256 * 4)), dim3(256),
                     0, stream, x, A_hi, A_lo);
  hipLaunchKernelGGL(split_w_kernel, dim3(32, 16), dim3(256), 0, stream,
                     in_proj_w, Wt_hi, Wt_lo);

  // 1) in_proj via split-bf16 MFMA: xz = x @ in_proj_w + b  [4096 x 1024]
  hipLaunchKernelGGL(in_proj_mfma_kernel, dim3(1024 / 128, NROWS / 128),
                     dim3(256), 0, stream, A_hi, A_lo, Wt_hi, Wt_lo,
                     in_proj_b, xz);

  // 2) depthwise causal conv on first half of xz -> xc [4096 x 512]
  {
    int total = NROWS * DM;
    hipLaunchKernelGGL(conv_kernel, dim3((total + 255) / 256), dim3(256), 0,
                       stream, xz, conv_w, conv_b, xc);
  }
  // 3) x_proj: xp = xc @ x_proj_w + b   [4096 x 160]
  {
    dim3 grid((160 + 63) / 64, NROWS / 64);
    hipLaunchKernelGGL((gemm_bias_kernel<0>), grid, dim3(256), 0, stream,
                       xc, DM, x_proj_w, 160, x_proj_b, xp, 160,
                       NROWS, 160, DM);
  }
  // 4) dt = softplus(xp[:, :32] @ dt_proj_w + b)  [4096 x 512]
  {
    dim3 grid(DM / 64, NROWS / 64);
    hipLaunchKernelGGL((gemm_bias_kernel<1>), grid, dim3(256), 0, stream,
                       xp, 160, dt_proj_w, DM, dt_proj_b, dtb, DM,
                       NROWS, DM, DTR);
  }
  // 5) chunked selective scan
  {
    dim3 grid((BSZ * DM * NC) / 4);  // 8192 blocks, 4 waves each
    hipLaunchKernelGGL(scan_phase1, grid, dim3(256), 0, stream,
                       dtb, xc, xp, A_log, B_param, hout, sdt);
    hipLaunchKernelGGL(scan_phase2, dim3((BSZ * DM) / 4), dim3(256), 0, stream,
                       A_log, hout, sdt);
    hipLaunchKernelGGL(scan_phase3, grid, dim3(256), 0, stream,
                       dtb, xc, xz, xp, A_log, B_param, C_param, D_param,
                       hout, out);
  }
}

// Round 5
// 305.600 us; speedup vs baseline: 3.6903x; 1.0068x over previous
//
#include <hip/hip_runtime.h>
#include <hip/hip_bf16.h>

// Problem constants (StateSpaceLayer): B=2, L=2048, D_MODEL=512, D_STATE=64,
// D_CONV=4, DT_RANK=32. All inputs/outputs fp32.
#define BSZ 2
#define SEQL 2048
#define DM 512
#define DST 64
#define DCONV 4
#define DTR 32
#define NROWS (BSZ * SEQL)   // 4096 flattened (b, t) rows

// Chunked scan decomposition
#define NC 32   // chunks per sequence
#define CL 64   // chunk length (NC*CL == SEQL)

// Combined projection output layout: xpd[row][640]
//   cols [0,64)   = Bp,  cols [64,128) = Cp,  cols [128,640) = softplus(dt)
#define XPD_LD 640

typedef unsigned short u16;
typedef short bf16x8 __attribute__((ext_vector_type(8)));
typedef float f32x4 __attribute__((ext_vector_type(4)));

// fp32 -> bf16 RNE split helpers (bit ops)
__device__ __forceinline__ u16 f2bf(float f) {
  unsigned u = __float_as_uint(f);
  return (u16)((u + 0x7FFFu + ((u >> 16) & 1u)) >> 16);
}
__device__ __forceinline__ float bf2f(u16 h) {
  return __uint_as_float(((unsigned)h) << 16);
}

// async global->LDS, 16B per lane (dest = wave-uniform base + lane*16)
__device__ __forceinline__ void gload_lds16(const u16* g, u16* l) {
  __builtin_amdgcn_global_load_lds(
      (const __attribute__((address_space(1))) void*)(const void*)g,
      (__attribute__((address_space(3))) void*)(void*)l, 16, 0, 0);
}

// ---------------------------------------------------------------------------
// Split conversion kernels.
// split_x: x [4096][512] f32 -> A_hi, A_lo bf16 (row-major)
// split_w: W [512][1024] f32 -> Wt_hi, Wt_lo bf16 TRANSPOSED [1024][512]
// ---------------------------------------------------------------------------
__global__ __launch_bounds__(256) void split_x_kernel(
    const float* __restrict__ x, u16* __restrict__ hi, u16* __restrict__ lo) {
  int idx = (blockIdx.x * 256 + threadIdx.x) * 4;  // over NROWS*DM
  float4 v = *(const float4*)(x + idx);
  ushort4 h, l;
  h.x = f2bf(v.x); l.x = f2bf(v.x - bf2f(h.x));
  h.y = f2bf(v.y); l.y = f2bf(v.y - bf2f(h.y));
  h.z = f2bf(v.z); l.z = f2bf(v.z - bf2f(h.z));
  h.w = f2bf(v.w); l.w = f2bf(v.w - bf2f(h.w));
  *(ushort4*)(hi + idx) = h;
  *(ushort4*)(lo + idx) = l;
}

__global__ __launch_bounds__(256) void split_w_kernel(
    const float* __restrict__ W, u16* __restrict__ Wt_hi,
    u16* __restrict__ Wt_lo) {
  __shared__ u16 shi[32][33], slo[32][33];
  const int n0 = blockIdx.x * 32;  // 32 blocks over N=1024
  const int k0 = blockIdx.y * 32;  // 16 blocks over K=512
  const int i = threadIdx.x >> 5;  // 0..7
  const int j = threadIdx.x & 31;
#pragma unroll
  for (int r = 0; r < 4; ++r) {
    int k = i + r * 8;
    float v = W[(size_t)(k0 + k) * 1024 + n0 + j];
    u16 h = f2bf(v);
    shi[k][j] = h;
    slo[k][j] = f2bf(v - bf2f(h));
  }
  __syncthreads();
#pragma unroll
  for (int r = 0; r < 4; ++r) {
    int n = i + r * 8;  // row of Wt within tile
    Wt_hi[(size_t)(n0 + n) * 512 + k0 + j] = shi[j][n];
    Wt_lo[(size_t)(n0 + n) * 512 + k0 + j] = slo[j][n];
  }
}

// ---------------------------------------------------------------------------
// Combined projection weight: Wt_c [640][512] bf16 split, transposed.
//   row r<128:  Wt_c[r][k] = x_proj_w[k][32+r]                 (Bp/Cp cols)
//   row 128+d:  Wt_c[128+d][k] = sum_j x_proj_w[k][j]*dt_proj_w[j][d], j<32
// bias_c[640]: r<128: x_proj_b[32+r]; 128+d: x_proj_b[:32]@dt_w[:,d] + dt_b[d]
// ---------------------------------------------------------------------------
__global__ __launch_bounds__(256) void w_combine_kernel(
    const float* __restrict__ xw, const float* __restrict__ dw,
    u16* __restrict__ Wt_hi, u16* __restrict__ Wt_lo) {
  int idx = blockIdx.x * 256 + threadIdx.x;  // over 640*512
  int r = idx >> 9;
  int k = idx & 511;
  float v;
  if (r < 128) {
    v = xw[(size_t)k * 160 + 32 + r];
  } else {
    int d = r - 128;
    float s = 0.f;
#pragma unroll
    for (int j = 0; j < DTR; ++j) s += xw[(size_t)k * 160 + j] * dw[(size_t)j * DM + d];
    v = s;
  }
  u16 h = f2bf(v);
  Wt_hi[idx] = h;
  Wt_lo[idx] = f2bf(v - bf2f(h));
}

__global__ __launch_bounds__(256) void bias_combine_kernel(
    const float* __restrict__ xb, const float* __restrict__ dw,
    const float* __restrict__ db, float* __restrict__ bias_c) {
  int r = blockIdx.x * 256 + threadIdx.x;
  if (r >= 640) return;
  float v;
  if (r < 128) {
    v = xb[32 + r];
  } else {
    int d = r - 128;
    float s = db[d];
#pragma unroll
    for (int j = 0; j < DTR; ++j) s += xb[j] * dw[(size_t)j * DM + d];
    v = s;
  }
  bias_c[r] = v;
}

// ---------------------------------------------------------------------------
// Split-bf16 MFMA GEMM: C[4096][N] = A[4096][512] @ Bt^T + bias
//   C = Ah@Wh + Ah@Wl + Al@Wh  (fp32 MFMA accumulation; lo*lo dropped)
// Tile 128x128xBK32, 4 waves (each 64x64: 4x4 frags of 16x16x32 bf16 MFMA).
// LDS: 4 arrays [128 rows][32 k] bf16, 8KB each. XOR swizzle on the 16B
// quarter index (q ^= (row>>1)&3) applied on the pre-swizzled global source
// (linear global_load_lds dest) and on the ds_read -> 2-way free.
// Softplus applied to cols >= act_from (block-aligned).
// ---------------------------------------------------------------------------
__global__ __launch_bounds__(256) void mfma_split_gemm(
    const u16* __restrict__ A_hi, const u16* __restrict__ A_lo,
    const u16* __restrict__ Bt_hi, const u16* __restrict__ Bt_lo,
    const float* __restrict__ bias, float* __restrict__ C,
    int ldc, int act_from) {
  __shared__ alignas(16) u16 sAh[4096], sAl[4096], sBh[4096], sBl[4096];

  const int lane = threadIdx.x & 63;
  const int wv = threadIdx.x >> 6;
  const int bm = blockIdx.y * 128;
  const int bn = blockIdx.x * 128;
  const int fr = lane & 15;   // fragment row/col index
  const int q = lane >> 4;    // k-quarter (8 bf16 = 16B)

  const int st_rowc = lane >> 2;
  const int st_qd = lane & 3;

  const bf16x8 *pAh[4], *pAl[4], *pBh[4], *pBl[4];
#pragma unroll
  for (int t = 0; t < 4; ++t) {
    int ra = (wv >> 1) * 64 + t * 16 + fr;
    int ea = ra * 32 + ((q ^ ((ra >> 1) & 3)) * 8);
    pAh[t] = (const bf16x8*)(sAh + ea);
    pAl[t] = (const bf16x8*)(sAl + ea);
    int rb = (wv & 1) * 64 + t * 16 + fr;
    int eb = rb * 32 + ((q ^ ((rb >> 1) & 3)) * 8);
    pBh[t] = (const bf16x8*)(sBh + eb);
    pBl[t] = (const bf16x8*)(sBl + eb);
  }

  f32x4 zero = {0.f, 0.f, 0.f, 0.f};
  f32x4 acc[4][4];
#pragma unroll
  for (int i = 0; i < 4; ++i)
#pragma unroll
    for (int j = 0; j < 4; ++j) acc[i][j] = zero;

  auto stage = [&](int k0) {
#pragma unroll
    for (int i = 0; i < 2; ++i) {
      int c = wv + i * 4;
      int row = c * 16 + st_rowc;
      int qs = st_qd ^ ((row >> 1) & 3);
      size_t ga = (size_t)(bm + row) * 512 + k0 + qs * 8;
      size_t gb = (size_t)(bn + row) * 512 + k0 + qs * 8;
      gload_lds16(A_hi + ga, sAh + c * 512);
      gload_lds16(A_lo + ga, sAl + c * 512);
      gload_lds16(Bt_hi + gb, sBh + c * 512);
      gload_lds16(Bt_lo + gb, sBl + c * 512);
    }
  };

  stage(0);
  for (int kt = 0; kt < 16; ++kt) {
    __syncthreads();  // staging of tile kt complete
    bf16x8 ah[4], al[4], bh[4], bl[4];
#pragma unroll
    for (int t = 0; t < 4; ++t) {
      ah[t] = *pAh[t];
      al[t] = *pAl[t];
      bh[t] = *pBh[t];
      bl[t] = *pBl[t];
    }
    __syncthreads();  // all waves done reading LDS
    if (kt < 15) stage((kt + 1) * 32);  // async prefetch overlaps MFMAs
#pragma unroll
    for (int mi = 0; mi < 4; ++mi)
#pragma unroll
      for (int nj = 0; nj < 4; ++nj) {
        f32x4 a = acc[mi][nj];
        a = __builtin_amdgcn_mfma_f32_16x16x32_bf16(al[mi], bh[nj], a, 0, 0, 0);
        a = __builtin_amdgcn_mfma_f32_16x16x32_bf16(ah[mi], bl[nj], a, 0, 0, 0);
        a = __builtin_amdgcn_mfma_f32_16x16x32_bf16(ah[mi], bh[nj], a, 0, 0, 0);
        acc[mi][nj] = a;
      }
  }

  const bool act = (bn >= act_from);
  // Epilogue: D col = lane&15, row = (lane>>4)*4 + reg
#pragma unroll
  for (int mi = 0; mi < 4; ++mi) {
#pragma unroll
    for (int nj = 0; nj < 4; ++nj) {
      int row = bm + (wv >> 1) * 64 + mi * 16 + q * 4;
      int col = bn + (wv & 1) * 64 + nj * 16 + fr;
      float bs = bias[col];
#pragma unroll
      for (int e = 0; e < 4; ++e) {
        float v = acc[mi][nj][e] + bs;
        if (act) v = (v > 20.f) ? v : log1pf(expf(v));
        C[(size_t)(row + e) * ldc + col] = v;
      }
    }
  }
}

// ---------------------------------------------------------------------------
// Depthwise causal conv1d (K=4) fused with bf16 hi/lo split of the result
// (the split feeds the combined-projection MFMA GEMM as the A operand).
// ---------------------------------------------------------------------------
__global__ __launch_bounds__(256) void conv_split_kernel(
    const float* __restrict__ xz, const float* __restrict__ w,
    const float* __restrict__ cb, float* __restrict__ xc,
    u16* __restrict__ hi, u16* __restrict__ lo) {
  int idx = blockIdx.x * blockDim.x + threadIdx.x;  // over B*L*D
  if (idx >= NROWS * DM) return;
  int d = idx & (DM - 1);
  int t = (idx >> 9) & (SEQL - 1);
  int b = idx >> 20;
  float acc = cb[d];
#pragma unroll
  for (int k = 0; k < DCONV; ++k) {
    int ts = t + k - (DCONV - 1);
    if (ts >= 0)
      acc += w[d * DCONV + k] * xz[((size_t)(b * SEQL + ts)) * (2 * DM) + d];
  }
  xc[idx] = acc;
  u16 h = f2bf(acc);
  hi[idx] = h;
  lo[idx] = f2bf(acc - bf2f(h));
}

// ---------------------------------------------------------------------------
// Chunked selective scan. xpd layout: Bp = col n, Cp = col 64+n, dt = 128+d.
// ---------------------------------------------------------------------------
__global__ __launch_bounds__(256) void scan_phase1(
    const float* __restrict__ xpd, const float* __restrict__ xc,
    const float* __restrict__ A_log, const float* __restrict__ Bpar,
    float* __restrict__ hout, float* __restrict__ sdt_arr) {
  const int lane = threadIdx.x & 63;
  const int wid = (blockIdx.x << 2) + (threadIdx.x >> 6);  // ch*NC + c
  const int ch = wid >> 5;
  const int c = wid & (NC - 1);
  const int b = ch >> 9;
  const int d = ch & (DM - 1);
  const int n = lane;

  const float aq = -__expf(A_log[d * DST + n]) * 1.44269504f;
  const float bpn = Bpar[d * DST + n];
  float h = 0.f, sdt = 0.f;

  const size_t row0 = (size_t)b * SEQL + (size_t)c * CL;
  const float* dtp = xpd + row0 * XPD_LD + 128 + d;
  const float* up = xc + row0 * DM + d;
  const float* bp = xpd + row0 * XPD_LD + n;

  for (int t0 = 0; t0 < CL; t0 += 4) {
    float dtv[4], uv[4], bpt[4];
#pragma unroll
    for (int j = 0; j < 4; ++j) {
      dtv[j] = dtp[(size_t)(t0 + j) * XPD_LD];
      uv[j] = up[(size_t)(t0 + j) * DM];
      bpt[j] = bp[(size_t)(t0 + j) * XPD_LD];
    }
#pragma unroll
    for (int j = 0; j < 4; ++j) {
      float Ad = exp2f(dtv[j] * aq);
      h = Ad * h + (bpn * bpt[j]) * (dtv[j] * uv[j]);
      sdt += dtv[j];
    }
  }
  hout[(size_t)wid * DST + n] = h;
  if (lane == 0) sdt_arr[wid] = sdt;
}

__global__ __launch_bounds__(256) void scan_phase2(
    const float* __restrict__ A_log, float* __restrict__ hout,
    const float* __restrict__ sdt_arr) {
  const int lane = threadIdx.x & 63;
  const int ch = (blockIdx.x << 2) + (threadIdx.x >> 6);
  const int d = ch & (DM - 1);
  const float aq = -__expf(A_log[d * DST + lane]) * 1.44269504f;

  float tmp[NC], pa[NC];
#pragma unroll
  for (int c = 0; c < NC; ++c) {
    tmp[c] = hout[((size_t)ch * NC + c) * DST + lane];
    pa[c] = exp2f(aq * sdt_arr[ch * NC + c]);
  }
  float h = 0.f;
#pragma unroll
  for (int c = 0; c < NC; ++c) {
    hout[((size_t)ch * NC + c) * DST + lane] = h;
    h = pa[c] * h + tmp[c];
  }
}

__global__ __launch_bounds__(256) void scan_phase3(
    const float* __restrict__ xpd, const float* __restrict__ xc,
    const float* __restrict__ xz,
    const float* __restrict__ A_log, const float* __restrict__ Bpar,
    const float* __restrict__ Cpar, const float* __restrict__ Dpar,
    const float* __restrict__ hin, float* __restrict__ out) {
  __shared__ float W[4][16][68];

  const int lane = threadIdx.x & 63;
  const int wave = threadIdx.x >> 6;
  const int wid = (blockIdx.x << 2) + wave;
  const int ch = wid >> 5;
  const int c = wid & (NC - 1);
  const int b = ch >> 9;
  const int d = ch & (DM - 1);
  const int n = lane;

  const float aq = -__expf(A_log[d * DST + n]) * 1.44269504f;
  const float bpn = Bpar[d * DST + n];
  const float cpn = Cpar[d * DST + n];
  const float Dd = Dpar[d];
  float h = hin[(size_t)wid * DST + n];

  const size_t row0 = (size_t)b * SEQL + (size_t)c * CL;
  const float* dtp = xpd + row0 * XPD_LD + 128 + d;
  const float* up = xc + row0 * DM + d;
  const float* bp = xpd + row0 * XPD_LD + n;
  const float* cp = xpd + row0 * XPD_LD + 64 + n;

  const int tt = lane & 15;
  const int q = lane >> 4;

  for (int t0 = 0; t0 < CL; t0 += 16) {
#pragma unroll
    for (int g = 0; g < 16; g += 4) {
      float dtv[4], uv[4], bpt[4], cpt[4];
#pragma unroll
      for (int j = 0; j < 4; ++j) {
        size_t t = (size_t)(t0 + g + j);
        dtv[j] = dtp[t * XPD_LD];
        uv[j] = up[t * DM];
        bpt[j] = bp[t * XPD_LD];
        cpt[j] = cp[t * XPD_LD];
      }
#pragma unroll
      for (int j = 0; j < 4; ++j) {
        float Ad = exp2f(dtv[j] * aq);
        h = Ad * h + (bpn * bpt[j]) * (dtv[j] * uv[j]);
        W[wave][g + j][n] = (cpn * cpt[j]) * h;
      }
    }
    const float4* wr = (const float4*)&W[wave][tt][q * 16];
    float s = 0.f;
#pragma unroll
    for (int k2 = 0; k2 < 4; ++k2) {
      float4 v = wr[k2];
      s += (v.x + v.y) + (v.z + v.w);
    }
    s += __shfl_xor(s, 16, 64);
    s += __shfl_xor(s, 32, 64);
    if (lane < 16) {
      size_t t = (size_t)(t0 + lane);
      float u = up[t * DM];
      float zz = xz[(row0 + t) * (2 * DM) + DM + d];
      float y = s + Dd * u;
      float sil = zz / (1.f + __expf(-zz));
      out[(row0 + t) * DM + d] = y * sil;
    }
  }
}

// ---------------------------------------------------------------------------
extern "C" void kernel_launch(void* const* d_in, const int* in_sizes, int n_in,
                              void* d_out, int out_size, void* d_ws,
                              size_t ws_size, hipStream_t stream) {
  const float* x = (const float*)d_in[0];           // [B,L,DM]
  const float* in_proj_w = (const float*)d_in[1];   // [DM, 2DM]
  const float* in_proj_b = (const float*)d_in[2];   // [2DM]
  const float* conv_w = (const float*)d_in[3];      // [DM,1,4]
  const float* conv_b = (const float*)d_in[4];      // [DM]
  const float* x_proj_w = (const float*)d_in[5];    // [DM, 160]
  const float* x_proj_b = (const float*)d_in[6];    // [160]
  const float* dt_proj_w = (const float*)d_in[7];   // [32, DM]
  const float* dt_proj_b = (const float*)d_in[8];   // [DM]
  const float* A_log = (const float*)d_in[9];       // [DM, DST]
  const float* B_param = (const float*)d_in[10];    // [DM, DST]
  const float* C_param = (const float*)d_in[11];    // [DM, DST]
  const float* D_param = (const float*)d_in[12];    // [DM]
  float* out = (float*)d_out;

  // Workspace partition (~56 MB total).
  float* ws = (float*)d_ws;
  float* xz = ws;                            // NROWS*2DM   = 4,194,304 f
  float* xc = xz + (size_t)NROWS * 2 * DM;   // NROWS*DM    = 2,097,152 f
  float* xpd = xc + (size_t)NROWS * DM;      // NROWS*640   = 2,621,440 f
  float* hout = xpd + (size_t)NROWS * XPD_LD;  // 2,097,152 f
  float* sdt = hout + (size_t)BSZ * DM * NC * DST;  // 32,768 f
  float* bias_c = sdt + (size_t)BSZ * DM * NC;      // 640 f
  u16* A_hi = (u16*)(bias_c + 1024);         // 2,097,152 u16 (reused for xc)
  u16* A_lo = A_hi + (size_t)NROWS * DM;     // 2,097,152 u16
  u16* Wt_in_hi = A_lo + (size_t)NROWS * DM; // 1024*512 u16
  u16* Wt_in_lo = Wt_in_hi + (size_t)1024 * 512;
  u16* Wt_c_hi = Wt_in_lo + (size_t)1024 * 512;  // 640*512 u16
  u16* Wt_c_lo = Wt_c_hi + (size_t)640 * 512;

  // 0) operand prep: splits + combined projection weight/bias
  hipLaunchKernelGGL(split_x_kernel, dim3((NROWS * DM) / (256 * 4)), dim3(256),
                     0, stream, x, A_hi, A_lo);
  hipLaunchKernelGGL(split_w_kernel, dim3(32, 16), dim3(256), 0, stream,
                     in_proj_w, Wt_in_hi, Wt_in_lo);
  hipLaunchKernelGGL(w_combine_kernel, dim3((640 * 512) / 256), dim3(256), 0,
                     stream, x_proj_w, dt_proj_w, Wt_c_hi, Wt_c_lo);
  hipLaunchKernelGGL(bias_combine_kernel, dim3(3), dim3(256), 0, stream,
                     x_proj_b, dt_proj_w, dt_proj_b, bias_c);

  // 1) in_proj via split-bf16 MFMA: xz = x @ in_proj_w + b  [4096 x 1024]
  hipLaunchKernelGGL(mfma_split_gemm, dim3(1024 / 128, NROWS / 128),
                     dim3(256), 0, stream, A_hi, A_lo, Wt_in_hi, Wt_in_lo,
                     in_proj_b, xz, 1024, 1 << 30);

  // 2) depthwise causal conv + bf16 split of xc (overwrites A_hi/A_lo)
  {
    int total = NROWS * DM;
    hipLaunchKernelGGL(conv_split_kernel, dim3((total + 255) / 256), dim3(256),
                       0, stream, xz, conv_w, conv_b, xc, A_hi, A_lo);
  }
  // 3) fused x_proj+dt_proj: xpd = xc @ Wc + bias_c, softplus on cols>=128
  hipLaunchKernelGGL(mfma_split_gemm, dim3(640 / 128, NROWS / 128),
                     dim3(256), 0, stream, A_hi, A_lo, Wt_c_hi, Wt_c_lo,
                     bias_c, xpd, XPD_LD, 128);

  // 4) chunked selective scan
  {
    dim3 grid((BSZ * DM * NC) / 4);  // 8192 blocks, 4 waves each
    hipLaunchKernelGGL(scan_phase1, grid, dim3(256), 0, stream,
                       xpd, xc, A_log, B_param, hout, sdt);
    hipLaunchKernelGGL(scan_phase2, dim3((BSZ * DM) / 4), dim3(256), 0, stream,
                       A_log, hout, sdt);
    hipLaunchKernelGGL(scan_phase3, grid, dim3(256), 0, stream,
                       xpd, xc, xz, A_log, B_param, C_param, D_param,
                       hout, out);
  }
}

// Round 6
// 263.600 us; speedup vs baseline: 4.2783x; 1.1593x over previous
//
#include <hip/hip_runtime.h>
#include <hip/hip_bf16.h>

// Problem constants (StateSpaceLayer): B=2, L=2048, D_MODEL=512, D_STATE=64,
// D_CONV=4, DT_RANK=32. All inputs/outputs fp32.
#define BSZ 2
#define SEQL 2048
#define DM 512
#define DST 64
#define DCONV 4
#define DTR 32
#define NROWS (BSZ * SEQL)   // 4096 flattened (b, t) rows

// Chunked scan decomposition
#define NC 32   // chunks per sequence
#define CL 64   // chunk length (NC*CL == SEQL)

// Combined projection output layout: xpd[row][640]
//   cols [0,64)   = Bp,  cols [64,128) = Cp,  cols [128,640) = softplus(dt)
#define XPD_LD 640

typedef unsigned short u16;
typedef short bf16x8 __attribute__((ext_vector_type(8)));
typedef float f32x4 __attribute__((ext_vector_type(4)));

// fp32 -> bf16 RNE split helpers (bit ops)
__device__ __forceinline__ u16 f2bf(float f) {
  unsigned u = __float_as_uint(f);
  return (u16)((u + 0x7FFFu + ((u >> 16) & 1u)) >> 16);
}
__device__ __forceinline__ float bf2f(u16 h) {
  return __uint_as_float(((unsigned)h) << 16);
}

// async global->LDS, 16B per lane (dest = wave-uniform base + lane*16)
__device__ __forceinline__ void gload_lds16(const u16* g, u16* l) {
  __builtin_amdgcn_global_load_lds(
      (const __attribute__((address_space(1))) void*)(const void*)g,
      (__attribute__((address_space(3))) void*)(void*)l, 16, 0, 0);
}

// ---------------------------------------------------------------------------
// Split conversion kernels.
// ---------------------------------------------------------------------------
__global__ __launch_bounds__(256) void split_x_kernel(
    const float* __restrict__ x, u16* __restrict__ hi, u16* __restrict__ lo) {
  int idx = (blockIdx.x * 256 + threadIdx.x) * 4;  // over NROWS*DM
  float4 v = *(const float4*)(x + idx);
  ushort4 h, l;
  h.x = f2bf(v.x); l.x = f2bf(v.x - bf2f(h.x));
  h.y = f2bf(v.y); l.y = f2bf(v.y - bf2f(h.y));
  h.z = f2bf(v.z); l.z = f2bf(v.z - bf2f(h.z));
  h.w = f2bf(v.w); l.w = f2bf(v.w - bf2f(h.w));
  *(ushort4*)(hi + idx) = h;
  *(ushort4*)(lo + idx) = l;
}

__global__ __launch_bounds__(256) void split_w_kernel(
    const float* __restrict__ W, u16* __restrict__ Wt_hi,
    u16* __restrict__ Wt_lo) {
  __shared__ u16 shi[32][33], slo[32][33];
  const int n0 = blockIdx.x * 32;  // 32 blocks over N=1024
  const int k0 = blockIdx.y * 32;  // 16 blocks over K=512
  const int i = threadIdx.x >> 5;  // 0..7
  const int j = threadIdx.x & 31;
#pragma unroll
  for (int r = 0; r < 4; ++r) {
    int k = i + r * 8;
    float v = W[(size_t)(k0 + k) * 1024 + n0 + j];
    u16 h = f2bf(v);
    shi[k][j] = h;
    slo[k][j] = f2bf(v - bf2f(h));
  }
  __syncthreads();
#pragma unroll
  for (int r = 0; r < 4; ++r) {
    int n = i + r * 8;  // row of Wt within tile
    Wt_hi[(size_t)(n0 + n) * 512 + k0 + j] = shi[j][n];
    Wt_lo[(size_t)(n0 + n) * 512 + k0 + j] = slo[j][n];
  }
}

// ---------------------------------------------------------------------------
// Combined projection weight: Wt_c [640][512] bf16 split, transposed.
// ---------------------------------------------------------------------------
__global__ __launch_bounds__(256) void w_combine_kernel(
    const float* __restrict__ xw, const float* __restrict__ dw,
    u16* __restrict__ Wt_hi, u16* __restrict__ Wt_lo) {
  int idx = blockIdx.x * 256 + threadIdx.x;  // over 640*512
  int r = idx >> 9;
  int k = idx & 511;
  float v;
  if (r < 128) {
    v = xw[(size_t)k * 160 + 32 + r];
  } else {
    int d = r - 128;
    float s = 0.f;
#pragma unroll
    for (int j = 0; j < DTR; ++j) s += xw[(size_t)k * 160 + j] * dw[(size_t)j * DM + d];
    v = s;
  }
  u16 h = f2bf(v);
  Wt_hi[idx] = h;
  Wt_lo[idx] = f2bf(v - bf2f(h));
}

__global__ __launch_bounds__(256) void bias_combine_kernel(
    const float* __restrict__ xb, const float* __restrict__ dw,
    const float* __restrict__ db, float* __restrict__ bias_c) {
  int r = blockIdx.x * 256 + threadIdx.x;
  if (r >= 640) return;
  float v;
  if (r < 128) {
    v = xb[32 + r];
  } else {
    int d = r - 128;
    float s = db[d];
#pragma unroll
    for (int j = 0; j < DTR; ++j) s += xb[j] * dw[(size_t)j * DM + d];
    v = s;
  }
  bias_c[r] = v;
}

// ---------------------------------------------------------------------------
// in_proj split-bf16 MFMA GEMM (unchanged structure; act removed):
//   C[4096][1024] = Ah@Wh + Ah@Wl + Al@Wh + bias
// ---------------------------------------------------------------------------
__global__ __launch_bounds__(256) void mfma_split_gemm(
    const u16* __restrict__ A_hi, const u16* __restrict__ A_lo,
    const u16* __restrict__ Bt_hi, const u16* __restrict__ Bt_lo,
    const float* __restrict__ bias, float* __restrict__ C) {
  __shared__ alignas(16) u16 sAh[4096], sAl[4096], sBh[4096], sBl[4096];

  const int lane = threadIdx.x & 63;
  const int wv = threadIdx.x >> 6;
  const int bm = blockIdx.y * 128;
  const int bn = blockIdx.x * 128;
  const int fr = lane & 15;
  const int q = lane >> 4;

  const int st_rowc = lane >> 2;
  const int st_qd = lane & 3;

  const bf16x8 *pAh[4], *pAl[4], *pBh[4], *pBl[4];
#pragma unroll
  for (int t = 0; t < 4; ++t) {
    int ra = (wv >> 1) * 64 + t * 16 + fr;
    int ea = ra * 32 + ((q ^ ((ra >> 1) & 3)) * 8);
    pAh[t] = (const bf16x8*)(sAh + ea);
    pAl[t] = (const bf16x8*)(sAl + ea);
    int rb = (wv & 1) * 64 + t * 16 + fr;
    int eb = rb * 32 + ((q ^ ((rb >> 1) & 3)) * 8);
    pBh[t] = (const bf16x8*)(sBh + eb);
    pBl[t] = (const bf16x8*)(sBl + eb);
  }

  f32x4 zero = {0.f, 0.f, 0.f, 0.f};
  f32x4 acc[4][4];
#pragma unroll
  for (int i = 0; i < 4; ++i)
#pragma unroll
    for (int j = 0; j < 4; ++j) acc[i][j] = zero;

  auto stage = [&](int k0) {
#pragma unroll
    for (int i = 0; i < 2; ++i) {
      int c = wv + i * 4;
      int row = c * 16 + st_rowc;
      int qs = st_qd ^ ((row >> 1) & 3);
      size_t ga = (size_t)(bm + row) * 512 + k0 + qs * 8;
      size_t gb = (size_t)(bn + row) * 512 + k0 + qs * 8;
      gload_lds16(A_hi + ga, sAh + c * 512);
      gload_lds16(A_lo + ga, sAl + c * 512);
      gload_lds16(Bt_hi + gb, sBh + c * 512);
      gload_lds16(Bt_lo + gb, sBl + c * 512);
    }
  };

  stage(0);
  for (int kt = 0; kt < 16; ++kt) {
    __syncthreads();
    bf16x8 ah[4], al[4], bh[4], bl[4];
#pragma unroll
    for (int t = 0; t < 4; ++t) {
      ah[t] = *pAh[t];
      al[t] = *pAl[t];
      bh[t] = *pBh[t];
      bl[t] = *pBl[t];
    }
    __syncthreads();
    if (kt < 15) stage((kt + 1) * 32);
#pragma unroll
    for (int mi = 0; mi < 4; ++mi)
#pragma unroll
      for (int nj = 0; nj < 4; ++nj) {
        f32x4 a = acc[mi][nj];
        a = __builtin_amdgcn_mfma_f32_16x16x32_bf16(al[mi], bh[nj], a, 0, 0, 0);
        a = __builtin_amdgcn_mfma_f32_16x16x32_bf16(ah[mi], bl[nj], a, 0, 0, 0);
        a = __builtin_amdgcn_mfma_f32_16x16x32_bf16(ah[mi], bh[nj], a, 0, 0, 0);
        acc[mi][nj] = a;
      }
  }

#pragma unroll
  for (int mi = 0; mi < 4; ++mi) {
#pragma unroll
    for (int nj = 0; nj < 4; ++nj) {
      int row = bm + (wv >> 1) * 64 + mi * 16 + q * 4;
      int col = bn + (wv & 1) * 64 + nj * 16 + fr;
      float bs = bias[col];
#pragma unroll
      for (int e = 0; e < 4; ++e)
        C[(size_t)(row + e) * 1024 + col] = acc[mi][nj][e] + bs;
    }
  }
}

// ---------------------------------------------------------------------------
// xpd GEMM, resident-weight variant: C[4096][640] = A[4096][512] @ Bt^T + bias
// Block = 128 rows x 64 cols, 4 waves as 2x2 (wave tile 64x32).
// The block's whole B-panel (64 cols x 512 K, hi+lo bf16 = 128 KB) is staged
// into LDS ONCE; A fragments stream directly from global (L2-resident).
// -> ZERO barriers and zero staging in the K-loop: pure load->MFMA dataflow
// the compiler can pipeline. B LDS reads XOR-swizzled (chunk ^= col&7), with
// the same involution pre-applied on the gload source (rule: both sides).
// ---------------------------------------------------------------------------
__global__ __launch_bounds__(256) void xpd_gemm_kernel(
    const u16* __restrict__ A_hi, const u16* __restrict__ A_lo,
    const u16* __restrict__ Bt_hi, const u16* __restrict__ Bt_lo,
    const float* __restrict__ bias, float* __restrict__ C) {
  __shared__ alignas(16) u16 sBh[64 * 512];  // 64 KB
  __shared__ alignas(16) u16 sBl[64 * 512];  // 64 KB

  const int lane = threadIdx.x & 63;
  const int wv = threadIdx.x >> 6;
  const int wr = wv >> 1;          // wave row (0..1) -> 64-row half
  const int wc = wv & 1;           // wave col (0..1) -> 32-col half
  const int bm = blockIdx.y * 128;
  const int bn = blockIdx.x * 64;
  const int fr = lane & 15;
  const int q = lane >> 4;         // k-quarter within BK=32

  // --- stage B panel once: wave wv stages rows [wv*16, wv*16+16), hi+lo.
  // One gload_lds16 moves exactly one row (64 lanes x 16B = 1KB = 512 u16).
  // Source chunk pre-swizzled: lane l fetches global chunk l ^ (row&7).
  {
    const int r0 = wv * 16;
#pragma unroll
    for (int i = 0; i < 16; ++i) {
      int r = r0 + i;
      size_t g = (size_t)(bn + r) * 512 + (size_t)(lane ^ (r & 7)) * 8;
      gload_lds16(Bt_hi + g, sBh + r * 512);
      gload_lds16(Bt_lo + g, sBl + r * 512);
    }
  }
  __syncthreads();  // drains vmcnt -> B panel resident for the whole kernel

  // Per-thread A row bases and B column-rows
  size_t arow[4];
#pragma unroll
  for (int mi = 0; mi < 4; ++mi)
    arow[mi] = (size_t)(bm + wr * 64 + mi * 16 + fr) * 512;
  int bcol[2];
#pragma unroll
  for (int nj = 0; nj < 2; ++nj) bcol[nj] = wc * 32 + nj * 16 + fr;

  f32x4 zero = {0.f, 0.f, 0.f, 0.f};
  f32x4 acc[4][2];
#pragma unroll
  for (int i = 0; i < 4; ++i) {
    acc[i][0] = zero;
    acc[i][1] = zero;
  }

#pragma unroll 4
  for (int kt = 0; kt < 16; ++kt) {
    bf16x8 ah[4], al[4], bh[2], bl[2];
    const int kc = kt * 4 + q;  // 16B chunk index within the 64-chunk K range
#pragma unroll
    for (int nj = 0; nj < 2; ++nj) {
      int off = bcol[nj] * 512 + ((kc ^ (bcol[nj] & 7)) * 8);
      bh[nj] = *(const bf16x8*)(sBh + off);
      bl[nj] = *(const bf16x8*)(sBl + off);
    }
#pragma unroll
    for (int mi = 0; mi < 4; ++mi) {
      size_t ga = arow[mi] + kt * 32 + q * 8;
      ah[mi] = *(const bf16x8*)(A_hi + ga);
      al[mi] = *(const bf16x8*)(A_lo + ga);
    }
#pragma unroll
    for (int mi = 0; mi < 4; ++mi)
#pragma unroll
      for (int nj = 0; nj < 2; ++nj) {
        f32x4 a = acc[mi][nj];
        a = __builtin_amdgcn_mfma_f32_16x16x32_bf16(al[mi], bh[nj], a, 0, 0, 0);
        a = __builtin_amdgcn_mfma_f32_16x16x32_bf16(ah[mi], bl[nj], a, 0, 0, 0);
        a = __builtin_amdgcn_mfma_f32_16x16x32_bf16(ah[mi], bh[nj], a, 0, 0, 0);
        acc[mi][nj] = a;
      }
  }

  // Epilogue: D col = lane&15, row = (lane>>4)*4 + reg. Bias only (softplus
  // applied by a separate pass over the dt region).
#pragma unroll
  for (int mi = 0; mi < 4; ++mi) {
#pragma unroll
    for (int nj = 0; nj < 2; ++nj) {
      int row = bm + wr * 64 + mi * 16 + q * 4;
      int col = bn + wc * 32 + nj * 16 + fr;
      float bs = bias[col];
#pragma unroll
      for (int e = 0; e < 4; ++e)
        C[(size_t)(row + e) * XPD_LD + col] = acc[mi][nj][e] + bs;
    }
  }
}

// ---------------------------------------------------------------------------
// Softplus over the dt region of xpd (cols 128..640), in place.
// ---------------------------------------------------------------------------
__global__ __launch_bounds__(256) void softplus_kernel(float* __restrict__ xpd) {
  int idx = blockIdx.x * 256 + threadIdx.x;  // over (NROWS*512)/4
  int row = idx >> 7;          // 128 float4 per row
  int cq = (idx & 127) * 4;
  float* p = xpd + (size_t)row * XPD_LD + 128 + cq;
  float4 v = *(float4*)p;
  v.x = (v.x > 20.f) ? v.x : log1pf(expf(v.x));
  v.y = (v.y > 20.f) ? v.y : log1pf(expf(v.y));
  v.z = (v.z > 20.f) ? v.z : log1pf(expf(v.z));
  v.w = (v.w > 20.f) ? v.w : log1pf(expf(v.w));
  *(float4*)p = v;
}

// ---------------------------------------------------------------------------
// Depthwise causal conv1d (K=4) fused with bf16 hi/lo split of the result.
// ---------------------------------------------------------------------------
__global__ __launch_bounds__(256) void conv_split_kernel(
    const float* __restrict__ xz, const float* __restrict__ w,
    const float* __restrict__ cb, float* __restrict__ xc,
    u16* __restrict__ hi, u16* __restrict__ lo) {
  int idx = blockIdx.x * blockDim.x + threadIdx.x;  // over B*L*D
  if (idx >= NROWS * DM) return;
  int d = idx & (DM - 1);
  int t = (idx >> 9) & (SEQL - 1);
  int b = idx >> 20;
  float acc = cb[d];
#pragma unroll
  for (int k = 0; k < DCONV; ++k) {
    int ts = t + k - (DCONV - 1);
    if (ts >= 0)
      acc += w[d * DCONV + k] * xz[((size_t)(b * SEQL + ts)) * (2 * DM) + d];
  }
  xc[idx] = acc;
  u16 h = f2bf(acc);
  hi[idx] = h;
  lo[idx] = f2bf(acc - bf2f(h));
}

// ---------------------------------------------------------------------------
// Chunked selective scan. xpd layout: Bp = col n, Cp = col 64+n, dt = 128+d.
// ---------------------------------------------------------------------------
__global__ __launch_bounds__(256) void scan_phase1(
    const float* __restrict__ xpd, const float* __restrict__ xc,
    const float* __restrict__ A_log, const float* __restrict__ Bpar,
    float* __restrict__ hout, float* __restrict__ sdt_arr) {
  const int lane = threadIdx.x & 63;
  const int wid = (blockIdx.x << 2) + (threadIdx.x >> 6);  // ch*NC + c
  const int ch = wid >> 5;
  const int c = wid & (NC - 1);
  const int b = ch >> 9;
  const int d = ch & (DM - 1);
  const int n = lane;

  const float aq = -__expf(A_log[d * DST + n]) * 1.44269504f;
  const float bpn = Bpar[d * DST + n];
  float h = 0.f, sdt = 0.f;

  const size_t row0 = (size_t)b * SEQL + (size_t)c * CL;
  const float* dtp = xpd + row0 * XPD_LD + 128 + d;
  const float* up = xc + row0 * DM + d;
  const float* bp = xpd + row0 * XPD_LD + n;

  for (int t0 = 0; t0 < CL; t0 += 4) {
    float dtv[4], uv[4], bpt[4];
#pragma unroll
    for (int j = 0; j < 4; ++j) {
      dtv[j] = dtp[(size_t)(t0 + j) * XPD_LD];
      uv[j] = up[(size_t)(t0 + j) * DM];
      bpt[j] = bp[(size_t)(t0 + j) * XPD_LD];
    }
#pragma unroll
    for (int j = 0; j < 4; ++j) {
      float Ad = exp2f(dtv[j] * aq);
      h = Ad * h + (bpn * bpt[j]) * (dtv[j] * uv[j]);
      sdt += dtv[j];
    }
  }
  hout[(size_t)wid * DST + n] = h;
  if (lane == 0) sdt_arr[wid] = sdt;
}

__global__ __launch_bounds__(256) void scan_phase2(
    const float* __restrict__ A_log, float* __restrict__ hout,
    const float* __restrict__ sdt_arr) {
  const int lane = threadIdx.x & 63;
  const int ch = (blockIdx.x << 2) + (threadIdx.x >> 6);
  const int d = ch & (DM - 1);
  const float aq = -__expf(A_log[d * DST + lane]) * 1.44269504f;

  float tmp[NC], pa[NC];
#pragma unroll
  for (int c = 0; c < NC; ++c) {
    tmp[c] = hout[((size_t)ch * NC + c) * DST + lane];
    pa[c] = exp2f(aq * sdt_arr[ch * NC + c]);
  }
  float h = 0.f;
#pragma unroll
  for (int c = 0; c < NC; ++c) {
    hout[((size_t)ch * NC + c) * DST + lane] = h;
    h = pa[c] * h + tmp[c];
  }
}

__global__ __launch_bounds__(256) void scan_phase3(
    const float* __restrict__ xpd, const float* __restrict__ xc,
    const float* __restrict__ xz,
    const float* __restrict__ A_log, const float* __restrict__ Bpar,
    const float* __restrict__ Cpar, const float* __restrict__ Dpar,
    const float* __restrict__ hin, float* __restrict__ out) {
  __shared__ float W[4][16][68];

  const int lane = threadIdx.x & 63;
  const int wave = threadIdx.x >> 6;
  const int wid = (blockIdx.x << 2) + wave;
  const int ch = wid >> 5;
  const int c = wid & (NC - 1);
  const int b = ch >> 9;
  const int d = ch & (DM - 1);
  const int n = lane;

  const float aq = -__expf(A_log[d * DST + n]) * 1.44269504f;
  const float bpn = Bpar[d * DST + n];
  const float cpn = Cpar[d * DST + n];
  const float Dd = Dpar[d];
  float h = hin[(size_t)wid * DST + n];

  const size_t row0 = (size_t)b * SEQL + (size_t)c * CL;
  const float* dtp = xpd + row0 * XPD_LD + 128 + d;
  const float* up = xc + row0 * DM + d;
  const float* bp = xpd + row0 * XPD_LD + n;
  const float* cp = xpd + row0 * XPD_LD + 64 + n;

  const int tt = lane & 15;
  const int q = lane >> 4;

  for (int t0 = 0; t0 < CL; t0 += 16) {
#pragma unroll
    for (int g = 0; g < 16; g += 4) {
      float dtv[4], uv[4], bpt[4], cpt[4];
#pragma unroll
      for (int j = 0; j < 4; ++j) {
        size_t t = (size_t)(t0 + g + j);
        dtv[j] = dtp[t * XPD_LD];
        uv[j] = up[t * DM];
        bpt[j] = bp[t * XPD_LD];
        cpt[j] = cp[t * XPD_LD];
      }
#pragma unroll
      for (int j = 0; j < 4; ++j) {
        float Ad = exp2f(dtv[j] * aq);
        h = Ad * h + (bpn * bpt[j]) * (dtv[j] * uv[j]);
        W[wave][g + j][n] = (cpn * cpt[j]) * h;
      }
    }
    const float4* wr = (const float4*)&W[wave][tt][q * 16];
    float s = 0.f;
#pragma unroll
    for (int k2 = 0; k2 < 4; ++k2) {
      float4 v = wr[k2];
      s += (v.x + v.y) + (v.z + v.w);
    }
    s += __shfl_xor(s, 16, 64);
    s += __shfl_xor(s, 32, 64);
    if (lane < 16) {
      size_t t = (size_t)(t0 + lane);
      float u = up[t * DM];
      float zz = xz[(row0 + t) * (2 * DM) + DM + d];
      float y = s + Dd * u;
      float sil = zz / (1.f + __expf(-zz));
      out[(row0 + t) * DM + d] = y * sil;
    }
  }
}

// ---------------------------------------------------------------------------
extern "C" void kernel_launch(void* const* d_in, const int* in_sizes, int n_in,
                              void* d_out, int out_size, void* d_ws,
                              size_t ws_size, hipStream_t stream) {
  const float* x = (const float*)d_in[0];           // [B,L,DM]
  const float* in_proj_w = (const float*)d_in[1];   // [DM, 2DM]
  const float* in_proj_b = (const float*)d_in[2];   // [2DM]
  const float* conv_w = (const float*)d_in[3];      // [DM,1,4]
  const float* conv_b = (const float*)d_in[4];      // [DM]
  const float* x_proj_w = (const float*)d_in[5];    // [DM, 160]
  const float* x_proj_b = (const float*)d_in[6];    // [160]
  const float* dt_proj_w = (const float*)d_in[7];   // [32, DM]
  const float* dt_proj_b = (const float*)d_in[8];   // [DM]
  const float* A_log = (const float*)d_in[9];       // [DM, DST]
  const float* B_param = (const float*)d_in[10];    // [DM, DST]
  const float* C_param = (const float*)d_in[11];    // [DM, DST]
  const float* D_param = (const float*)d_in[12];    // [DM]
  float* out = (float*)d_out;

  // Workspace partition (~56 MB total).
  float* ws = (float*)d_ws;
  float* xz = ws;                            // NROWS*2DM   = 4,194,304 f
  float* xc = xz + (size_t)NROWS * 2 * DM;   // NROWS*DM    = 2,097,152 f
  float* xpd = xc + (size_t)NROWS * DM;      // NROWS*640   = 2,621,440 f
  float* hout = xpd + (size_t)NROWS * XPD_LD;  // 2,097,152 f
  float* sdt = hout + (size_t)BSZ * DM * NC * DST;  // 32,768 f
  float* bias_c = sdt + (size_t)BSZ * DM * NC;      // 640 f
  u16* A_hi = (u16*)(bias_c + 1024);         // 2,097,152 u16 (reused for xc)
  u16* A_lo = A_hi + (size_t)NROWS * DM;     // 2,097,152 u16
  u16* Wt_in_hi = A_lo + (size_t)NROWS * DM; // 1024*512 u16
  u16* Wt_in_lo = Wt_in_hi + (size_t)1024 * 512;
  u16* Wt_c_hi = Wt_in_lo + (size_t)1024 * 512;  // 640*512 u16
  u16* Wt_c_lo = Wt_c_hi + (size_t)640 * 512;

  // 0) operand prep: splits + combined projection weight/bias
  hipLaunchKernelGGL(split_x_kernel, dim3((NROWS * DM) / (256 * 4)), dim3(256),
                     0, stream, x, A_hi, A_lo);
  hipLaunchKernelGGL(split_w_kernel, dim3(32, 16), dim3(256), 0, stream,
                     in_proj_w, Wt_in_hi, Wt_in_lo);
  hipLaunchKernelGGL(w_combine_kernel, dim3((640 * 512) / 256), dim3(256), 0,
                     stream, x_proj_w, dt_proj_w, Wt_c_hi, Wt_c_lo);
  hipLaunchKernelGGL(bias_combine_kernel, dim3(3), dim3(256), 0, stream,
                     x_proj_b, dt_proj_w, dt_proj_b, bias_c);

  // 1) in_proj via split-bf16 MFMA: xz = x @ in_proj_w + b  [4096 x 1024]
  hipLaunchKernelGGL(mfma_split_gemm, dim3(1024 / 128, NROWS / 128),
                     dim3(256), 0, stream, A_hi, A_lo, Wt_in_hi, Wt_in_lo,
                     in_proj_b, xz);

  // 2) depthwise causal conv + bf16 split of xc (overwrites A_hi/A_lo)
  {
    int total = NROWS * DM;
    hipLaunchKernelGGL(conv_split_kernel, dim3((total + 255) / 256), dim3(256),
                       0, stream, xz, conv_w, conv_b, xc, A_hi, A_lo);
  }
  // 3) fused x_proj+dt_proj via resident-weight GEMM, then softplus pass
  hipLaunchKernelGGL(xpd_gemm_kernel, dim3(640 / 64, NROWS / 128),
                     dim3(256), 0, stream, A_hi, A_lo, Wt_c_hi, Wt_c_lo,
                     bias_c, xpd);
  hipLaunchKernelGGL(softplus_kernel, dim3((NROWS * 512) / (256 * 4)),
                     dim3(256), 0, stream, xpd);

  // 4) chunked selective scan
  {
    dim3 grid((BSZ * DM * NC) / 4);  // 8192 blocks, 4 waves each
    hipLaunchKernelGGL(scan_phase1, grid, dim3(256), 0, stream,
                       xpd, xc, A_log, B_param, hout, sdt);
    hipLaunchKernelGGL(scan_phase2, dim3((BSZ * DM) / 4), dim3(256), 0, stream,
                       A_log, hout, sdt);
    hipLaunchKernelGGL(scan_phase3, grid, dim3(256), 0, stream,
                       xpd, xc, xz, A_log, B_param, C_param, D_param,
                       hout, out);
  }
}